// Round 6
// baseline (1799.024 us; speedup 1.0000x reference)
//
#include <hip/hip_runtime.h>
#include <cstdint>
#include <cstddef>

// BiLSTM-CRF forward, MI355X fp32 implementation.
// Pipeline: prep -> proj1(emb gather GEMM) -> lstm1(512 chains) -> proj2
//           -> lstm2(64 chains) -> emission -> viterbi(+backtrace).
//
// R7/R8/R9: in-wave K-slice reduction (resubmitted; infra timeouts R8, R9).
//   R6 post-mortem: chain pairing improved per-interval throughput but the
//   dispatch is bounded by the LONGEST chain's serial step count -> regressed.
//   Reverted. This round attacks cycles-per-step directly.
//   Lane remap t -> (j = t>>2, q = t&3): the 4 K-slice partials of state j
//   sit in 4 adjacent lanes of ONE wave -> reduce = 2x shfl_xor (quad DPP),
//   no psum LDS round-trip, no 2-wave serial reducer (all 512 threads
//   compute gates redundantly in parallel). h ping-pong in LDS gives ONE
//   raw barrier per step (BAR_LDS never drains vmcnt; xv loads stay in
//   flight 2 steps ahead; hn stores fire-and-forget).
//   h stored in 4 pad-36 slices: matvec's 4-address broadcast read is
//   bank-conflict-free. Partial-sum association (p0+p1)+(p2+p3) preserved
//   bit-exactly vs the R5 kernel.
//   Step model: 512 cyc FMA-issue floor + ~250 latency ~= 800 cyc vs ~2050.

#define B_    32
#define NSEG_ 8
#define S_    128
#define T_    1024
#define E_    256
#define HD_   128
#define G_    512   // 4*HD
#define K_    16

#define PIN4(v) asm volatile("" : "+v"((v).x), "+v"((v).y), "+v"((v).z), "+v"((v).w))

// Barrier that does NOT drain vmcnt: LDS writes made visible (lgkmcnt(0)),
// rendezvous, then a hard scheduling fence so following LDS reads can't
// hoist above the barrier (rule #18).
#define BAR_LDS() do {                                        \
    asm volatile("s_waitcnt lgkmcnt(0)" ::: "memory");        \
    __builtin_amdgcn_s_barrier();                             \
    __builtin_amdgcn_sched_barrier(0);                        \
} while (0)

// ---------------- prep: seg offsets, fused+permuted bias, permuted Wih^T ----------------
// Gate-interleaved column n in [0,1024): dir=n>>9, j=(n>>2)&127, g=n&3
// maps to LSTM gate row (g*128+j) of direction dir.
__global__ void prep_kernel(const int* __restrict__ lengths,
                            int* __restrict__ seg_off, int* __restrict__ new_len,
                            const float* __restrict__ bih_f, const float* __restrict__ bhh_f,
                            const float* __restrict__ bih_b, const float* __restrict__ bhh_b,
                            float* __restrict__ bias1,
                            const float* __restrict__ Wih_f, const float* __restrict__ Wih_b,
                            float* __restrict__ WT1)
{
    int gtid = blockIdx.x * blockDim.x + threadIdx.x;
    if (gtid < B_) {
        int acc = 0;
        for (int s = 0; s < NSEG_; s++) { seg_off[gtid*NSEG_ + s] = acc; acc += lengths[gtid*NSEG_ + s]; }
        new_len[gtid] = acc;
    }
    if (gtid < 1024) {
        int n = gtid, dir = n >> 9, j = (n >> 2) & 127, g = n & 3;
        int row = g*128 + j;
        bias1[n] = dir ? (bih_b[row] + bhh_b[row]) : (bih_f[row] + bhh_f[row]);
    }
    // WT1[k][n] (256 x 1024): column n holds Wih row (g*128+j) of dir.
    for (int e = gtid; e < 256*1024; e += gridDim.x * blockDim.x) {
        int k = e >> 10, n = e & 1023;
        int dir = n >> 9, j = (n >> 2) & 127, g = n & 3;
        int row = g*128 + j;
        WT1[e] = dir ? Wih_b[row*E_ + k] : Wih_f[row*E_ + k];
    }
}

// ---------------- projection GEMM: xproj[b][p][n] = A[p][:] . WT1[:][n] + bias1[n] ----------------
template <int MODE>
__global__ void __launch_bounds__(256, 4)
proj_kernel(const int* __restrict__ texts, const float* __restrict__ emb,
            const float* __restrict__ WT1, const float* __restrict__ bias1,
            const float* __restrict__ lstm_packed, float* __restrict__ xproj,
            const int* __restrict__ seg_off, const int* __restrict__ new_len)
{
    int b  = blockIdx.z;
    int nl = new_len[b];
    int p0 = blockIdx.x * 32;
    if (p0 >= nl) return;
    int j0 = blockIdx.y * 256;

    __shared__ __align__(16) float As[32][256];
    __shared__ const float* rowp[32];
    int tid = threadIdx.x;
    if (tid < 32) {
        int p = p0 + tid;
        const float* r = emb;  // dummy row for invalid p
        if (p < nl) {
            if (MODE == 0) {
                int sg = 0;
                #pragma unroll
                for (int q = 1; q < NSEG_; q++) if (seg_off[b*NSEG_ + q] <= p) sg = q;
                int t   = p - seg_off[b*NSEG_ + sg];
                int tok = texts[(b*NSEG_ + sg)*S_ + t];
                r = emb + (size_t)tok * E_;
            } else {
                r = lstm_packed + ((size_t)b*T_ + p) * 256;
            }
        }
        rowp[tid] = r;
    }
    __syncthreads();
    #pragma unroll 4
    for (int i = 0; i < 32; i++) As[i][tid] = rowp[i][tid];
    __syncthreads();

    int pg = tid >> 6;
    int jg = tid & 63;
    int j  = j0 + jg*4;
    float acc[8][4];
    #pragma unroll
    for (int i = 0; i < 8; i++) { acc[i][0]=0.f; acc[i][1]=0.f; acc[i][2]=0.f; acc[i][3]=0.f; }

    const float* wbase = WT1 + j;
    for (int k = 0; k < 256; k += 4) {
        float4 w0 = *(const float4*)(wbase + (size_t)(k+0)*1024);
        float4 w1 = *(const float4*)(wbase + (size_t)(k+1)*1024);
        float4 w2 = *(const float4*)(wbase + (size_t)(k+2)*1024);
        float4 w3 = *(const float4*)(wbase + (size_t)(k+3)*1024);
        #pragma unroll
        for (int i = 0; i < 8; i++) {
            float4 a = *(const float4*)&As[pg*8 + i][k];
            acc[i][0] = fmaf(a.w, w3.x, fmaf(a.z, w2.x, fmaf(a.y, w1.x, fmaf(a.x, w0.x, acc[i][0]))));
            acc[i][1] = fmaf(a.w, w3.y, fmaf(a.z, w2.y, fmaf(a.y, w1.y, fmaf(a.x, w0.y, acc[i][1]))));
            acc[i][2] = fmaf(a.w, w3.z, fmaf(a.z, w2.z, fmaf(a.y, w1.z, fmaf(a.x, w0.z, acc[i][2]))));
            acc[i][3] = fmaf(a.w, w3.w, fmaf(a.z, w2.w, fmaf(a.y, w1.w, fmaf(a.x, w0.w, acc[i][3]))));
        }
    }
    float4 bs = *(const float4*)(bias1 + j);
    #pragma unroll
    for (int i = 0; i < 8; i++) {
        int p = p0 + pg*8 + i;
        if (p < nl) {
            float4 r;
            r.x = acc[i][0] + bs.x; r.y = acc[i][1] + bs.y;
            r.z = acc[i][2] + bs.z; r.w = acc[i][3] + bs.w;
            *(float4*)(xproj + (((size_t)b*T_ + p) << 10) + j) = r;
        }
    }
}

// ---------------- LSTM chain v7: in-wave K-slice reduction ----------------
__device__ __forceinline__ float sig_f(float x) { return 1.0f / (1.0f + __expf(-x)); }
__device__ __forceinline__ float tanh_f(float x) {
    float xc = fminf(fmaxf(x, -15.0f), 15.0f);
    float e  = __expf(-2.0f * xc);
    return (1.0f - e) / (1.0f + e);
}

// Thread t -> state j = t>>2, K-slice q = t&3 (4 adjacent lanes per state).
// h in LDS ping-pong, 4 pad-36 slices: slice s holds h[32s..32s+32) at
// float offset s*36 (read: 4 distinct addrs/instr, 16-lane broadcast each,
// banks 4q+4i distinct -> conflict-free).
__device__ __forceinline__ void lstm_chain(
    const float* __restrict__ Whh,     // [512][128] row-major, this dir
    const float* __restrict__ xp,      // xproj for this b: [1024][1024] gate-interleaved
    float* __restrict__ outp,          // lstm_packed for this b: [1024][256]
    int p_base, int len, int dir, int rev,
    const float* __restrict__ h0, const float* __restrict__ c0,
    float* __restrict__ hT, float* __restrict__ cT)
{
    __shared__ __align__(16) float h_sh[2][4*36];   // 2 x 144 floats
    int t = threadIdx.x;          // 0..511
    int j = t >> 2, q = t & 3;

    // Weights: gate rows j+128g, k in [32q,32q+32). Pinned (128 VGPR).
    float4 w[4][8];
    #pragma unroll
    for (int g = 0; g < 4; g++) {
        const float4* wr = (const float4*)(Whh + (size_t)(j + 128*g) * HD_ + 32*q);
        #pragma unroll
        for (int i = 0; i < 8; i++) { w[g][i] = wr[i]; PIN4(w[g][i]); }
    }

    float c_reg = c0 ? c0[j] : 0.0f;    // replicated across the 4 q-lanes
    if (q == 0) h_sh[0][(j >> 5)*36 + (j & 31)] = h0 ? h0[j] : 0.0f;

    // x-contribution: one float4 (gates i,f,g,o) per (p, j); 4 lanes share it.
    const float4* xc  = (const float4*)(xp + (size_t)dir * G_) + j;
    const int     oco = dir * HD_ + j;

    float4 xvc = make_float4(0.f,0.f,0.f,0.f), xvn = xvc;
    if (len > 0) xvc = xc[(size_t)(p_base + (rev ? len-1 : 0)) << 8];
    if (len > 1) xvn = xc[(size_t)(p_base + (rev ? len-2 : 1)) << 8];
    __syncthreads();

    for (int it = 0; it < len; it++) {
        int p_out = p_base + (rev ? (len-1-it) : it);
        // rotate xv pipeline; prefetch it+2 (consumed ~2 steps later)
        float4 xu = xvc; xvc = xvn;
        if (it + 2 < len) xvn = xc[(size_t)(p_base + (rev ? (len-3-it) : (it+2))) << 8];

        // matvec partial over k in [32q,32q+32) for all 4 gates of state j
        const float4* hv = (const float4*)(h_sh[it & 1] + q*36);
        float4 a0 = make_float4(0.f,0.f,0.f,0.f);
        float4 a1 = a0, a2 = a0, a3 = a0;
        #pragma unroll
        for (int i = 0; i < 8; i++) {
            float4 h4 = hv[i];
            a0.x = fmaf(h4.x, w[0][i].x, a0.x); a0.y = fmaf(h4.y, w[0][i].y, a0.y);
            a0.z = fmaf(h4.z, w[0][i].z, a0.z); a0.w = fmaf(h4.w, w[0][i].w, a0.w);
            a1.x = fmaf(h4.x, w[1][i].x, a1.x); a1.y = fmaf(h4.y, w[1][i].y, a1.y);
            a1.z = fmaf(h4.z, w[1][i].z, a1.z); a1.w = fmaf(h4.w, w[1][i].w, a1.w);
            a2.x = fmaf(h4.x, w[2][i].x, a2.x); a2.y = fmaf(h4.y, w[2][i].y, a2.y);
            a2.z = fmaf(h4.z, w[2][i].z, a2.z); a2.w = fmaf(h4.w, w[2][i].w, a2.w);
            a3.x = fmaf(h4.x, w[3][i].x, a3.x); a3.y = fmaf(h4.y, w[3][i].y, a3.y);
            a3.z = fmaf(h4.z, w[3][i].z, a3.z); a3.w = fmaf(h4.w, w[3][i].w, a3.w);
        }
        float4 part;
        part.x = (a0.x+a0.y)+(a0.z+a0.w);
        part.y = (a1.x+a1.y)+(a1.z+a1.w);
        part.z = (a2.x+a2.y)+(a2.z+a2.w);
        part.w = (a3.x+a3.y)+(a3.z+a3.w);
        // in-wave butterfly over the 4 q-lanes: (p0+p1)+(p2+p3), bit-exact
        part.x += __shfl_xor(part.x, 1); part.y += __shfl_xor(part.y, 1);
        part.z += __shfl_xor(part.z, 1); part.w += __shfl_xor(part.w, 1);
        part.x += __shfl_xor(part.x, 2); part.y += __shfl_xor(part.y, 2);
        part.z += __shfl_xor(part.z, 2); part.w += __shfl_xor(part.w, 2);

        // gate math, replicated on all 4 q-lanes (identical inputs)
        float gi = xu.x + part.x;
        float gf = xu.y + part.y;
        float gg = xu.z + part.z;
        float go = xu.w + part.w;
        float cn = sig_f(gf) * c_reg + sig_f(gi) * tanh_f(gg);
        c_reg = cn;
        float hn = sig_f(go) * tanh_f(cn);
        if (q == 0) {
            h_sh[(it+1) & 1][(j >> 5)*36 + (j & 31)] = hn;
            outp[(size_t)p_out * 256 + oco] = hn;   // fire-and-forget
        }
        BAR_LDS();
    }

    if (q == 0 && hT != nullptr) {
        hT[j] = h_sh[len & 1][(j >> 5)*36 + (j & 31)];
        cT[j] = c_reg;
    }
}

__global__ void __launch_bounds__(512, 2)
lstm1_kernel(const int* __restrict__ lengths, const int* __restrict__ seg_off,
             const float* __restrict__ Whh_f, const float* __restrict__ Whh_b,
             const float* __restrict__ xproj, float* __restrict__ lstm_packed,
             float* __restrict__ hinit, float* __restrict__ cinit)
{
    int cid = blockIdx.x;                 // 512 = 32b * 8seg * 2dir
    int b = cid >> 4, seg = (cid >> 1) & 7, dir = cid & 1;
    int len = lengths[b*NSEG_ + seg];
    int pb  = seg_off[b*NSEG_ + seg];
    const float* Whh = dir ? Whh_b : Whh_f;
    float* hT = nullptr; float* cT = nullptr;
    if (seg == NSEG_ - 1) {               // final states feed LSTM2 init
        hT = hinit + (dir*B_ + b)*HD_;
        cT = cinit + (dir*B_ + b)*HD_;
    }
    lstm_chain(Whh, xproj + ((size_t)b << 20), lstm_packed + (size_t)b*T_*256,
               pb, len, dir, dir, nullptr, nullptr, hT, cT);
}

__global__ void __launch_bounds__(512, 2)
lstm2_kernel(const int* __restrict__ new_len,
             const float* __restrict__ Whh_f, const float* __restrict__ Whh_b,
             const float* __restrict__ xproj, float* __restrict__ lstm_packed,
             const float* __restrict__ hinit, const float* __restrict__ cinit)
{
    int cid = blockIdx.x;                 // 64 = 32b * 2dir
    int b = cid >> 1, dir = cid & 1;
    int len = new_len[b];
    const float* Whh = dir ? Whh_b : Whh_f;
    lstm_chain(Whh, xproj + ((size_t)b << 20), lstm_packed + (size_t)b*T_*256,
               0, len, dir, dir,
               hinit + (dir*B_ + b)*HD_, cinit + (dir*B_ + b)*HD_,
               nullptr, nullptr);
}

// ---------------- emission: em[b][p][s] = lstm2[b][p][:] . Wlin[s][:] + blin[s] ----------------
__global__ void __launch_bounds__(256)
emission_kernel(const float* __restrict__ lstm_packed, const float* __restrict__ Wlin,
                const float* __restrict__ blin, float* __restrict__ emis,
                const int* __restrict__ new_len)
{
    int b  = blockIdx.y;
    int nl = new_len[b];
    int p0 = blockIdx.x * 16;
    if (p0 >= nl) return;
    int pl = threadIdx.x >> 4, s = threadIdx.x & 15;
    int p  = p0 + pl;
    const float4* xr = (const float4*)(lstm_packed + ((size_t)b*T_ + p) * 256);
    const float4* wr = (const float4*)(Wlin + (size_t)s * 256);
    float ax = 0.f, ay = 0.f, az = 0.f, aw = 0.f;
    #pragma unroll
    for (int i = 0; i < 64; i++) {
        float4 a = xr[i]; float4 ww = wr[i];
        ax = fmaf(a.x, ww.x, ax); ay = fmaf(a.y, ww.y, ay);
        az = fmaf(a.z, ww.z, az); aw = fmaf(a.w, ww.w, aw);
    }
    if (p < nl) emis[((size_t)b*T_ + p)*K_ + s] = (ax + ay) + (az + aw) + blin[s];
}

// ---------------- Viterbi: one block (1 wave) per batch element ----------------
__global__ void __launch_bounds__(64)
viterbi_kernel(const float* __restrict__ emis, const float* __restrict__ start,
               const float* __restrict__ trans, const float* __restrict__ endv,
               const int* __restrict__ new_len, float* __restrict__ out)
{
    int b    = blockIdx.x;
    int nl   = new_len[b];
    int lane = threadIdx.x;          // 64 lanes: 4 q-groups x 16 states
    int s    = lane & 15, q4 = lane >> 4;

    __shared__ unsigned char hist[T_ * K_];   // 16 KB
    __shared__ unsigned char tagb[T_];

    float tr[4];
    #pragma unroll
    for (int jj = 0; jj < 4; jj++) tr[jj] = trans[(q4*4 + jj)*K_ + s];

    const float* em = emis + (size_t)b * T_ * K_;
    float sc = start[s] + em[s];     // p = 0 (always valid)

    for (int p = 1; p < nl; p++) {
        float e = em[p*K_ + s];
        float m = -3.4e38f; int a = 0;
        #pragma unroll
        for (int jj = 0; jj < 4; jj++) {
            int q   = q4*4 + jj;
            float sq = __shfl(sc, q, 16);
            float v  = sq + tr[jj];
            if (v > m) { m = v; a = q; }
        }
        #pragma unroll
        for (int d = 16; d < 64; d <<= 1) {
            float mo = __shfl_xor(m, d);
            int   ao = __shfl_xor(a, d);
            if (mo > m || (mo == m && ao < a)) { m = mo; a = ao; }
        }
        sc = m + e;
        if (lane < K_) hist[p*K_ + s] = (unsigned char)a;
    }

    float m = sc + endv[s]; int a = s;
    #pragma unroll
    for (int d = 1; d < 16; d <<= 1) {
        float mo = __shfl_xor(m, d);
        int   ao = __shfl_xor(a, d);
        if (mo > m || (mo == m && ao < a)) { m = mo; a = ao; }
    }
    int last = a;
    if (lane == 0) out[T_*B_ + b] = m;
    __syncthreads();

    for (int i = lane; i < T_; i += 64) tagb[i] = (unsigned char)last;
    __syncthreads();
    if (lane == 0) {
        int cur = last;
        for (int j = nl - 2; j >= 0; j--) {
            cur = hist[(j+1)*K_ + cur];
            tagb[j] = (unsigned char)cur;
        }
    }
    __syncthreads();
    for (int i = lane; i < T_; i += 64) out[(size_t)i*B_ + b] = (float)tagb[i];
}

// ---------------- host ----------------
extern "C" void kernel_launch(void* const* d_in, const int* in_sizes, int n_in,
                              void* d_out, int out_size, void* d_ws, size_t ws_size,
                              hipStream_t stream)
{
    (void)in_sizes; (void)n_in; (void)out_size; (void)ws_size;
    const int*   texts   = (const int*)  d_in[0];
    const int*   lengths = (const int*)  d_in[1];
    const float* emb     = (const float*)d_in[2];
    const float* Wih_f   = (const float*)d_in[3];
    const float* Whh_f   = (const float*)d_in[4];
    const float* bih_f   = (const float*)d_in[5];
    const float* bhh_f   = (const float*)d_in[6];
    const float* Wih_b   = (const float*)d_in[7];
    const float* Whh_b   = (const float*)d_in[8];
    const float* bih_b   = (const float*)d_in[9];
    const float* bhh_b   = (const float*)d_in[10];
    const float* Wlin    = (const float*)d_in[11];
    const float* blin    = (const float*)d_in[12];
    const float* c_start = (const float*)d_in[13];
    const float* c_trans = (const float*)d_in[14];
    const float* c_end   = (const float*)d_in[15];
    float* out = (float*)d_out;

    // workspace carve (~163 MB total, all 16B-aligned)
    char* w = (char*)d_ws;
    int*   seg_off     = (int*)(w);                      // 256 ints
    int*   new_len     = (int*)(w + 1024);               // 32 ints
    float* bias1       = (float*)(w + 4096);             // 1024 f
    float* WT1         = (float*)(w + 8192);             // 262144 f (1 MB)
    float* hinit       = (float*)(w + 8192 + 1048576);   // 8192 f
    float* cinit       = hinit + 8192;                   // 8192 f
    float* lstm_packed = cinit + 8192;                   // 32*1024*256 f (32 MB)
    float* xproj       = lstm_packed + (size_t)B_*T_*256;    // 32*1024*1024 f (128 MB)
    float* emis        = xproj + ((size_t)B_ << 20);         // 32*1024*16 f (2 MB)

    prep_kernel<<<128, 256, 0, stream>>>(lengths, seg_off, new_len,
                                         bih_f, bhh_f, bih_b, bhh_b, bias1,
                                         Wih_f, Wih_b, WT1);
    proj_kernel<0><<<dim3(32, 4, B_), 256, 0, stream>>>(texts, emb, WT1, bias1,
                                                        lstm_packed, xproj, seg_off, new_len);
    lstm1_kernel<<<512, 512, 0, stream>>>(lengths, seg_off, Whh_f, Whh_b,
                                          xproj, lstm_packed, hinit, cinit);
    proj_kernel<1><<<dim3(32, 4, B_), 256, 0, stream>>>(texts, emb, WT1, bias1,
                                                        lstm_packed, xproj, seg_off, new_len);
    lstm2_kernel<<<64, 512, 0, stream>>>(new_len, Whh_f, Whh_b,
                                         xproj, lstm_packed, hinit, cinit);
    emission_kernel<<<dim3(64, B_), 256, 0, stream>>>(lstm_packed, Wlin, blin, emis, new_len);
    viterbi_kernel<<<B_, 64, 0, stream>>>(emis, c_start, c_trans, c_end, new_len, out);
}

// Round 8
// 1776.664 us; speedup vs baseline: 1.0126x; 1.0126x over previous
//
#include <hip/hip_runtime.h>
#include <cstdint>
#include <cstddef>

// BiLSTM-CRF forward, MI355X fp32 implementation.
// Pipeline: prep -> proj1(emb gather GEMM) -> lstm1(512 chains) -> proj2
//           -> lstm2(64 chains) -> emission -> viterbi(+backtrace).
//
// R7..R9: in-wave K-slice reduction. MEASURED R6-round: lstm2 597->763us
//   REGRESSION. Counters: VALUBusy 2x (expected), LDS 1536 (expected), but
//   issue-cycles/step ~650->~1450. Cause theory: HIP __shfl_xor lowers to
//   ds_bpermute_b32 -> 16 DS-pipe ops/thread/step on the CU's single shared
//   LDS pipe (x8 waves), plus ~30cyc latency each inside the serial chain.
// R10/R11: replace the quad butterfly's __shfl_xor with DPP quad_perm
//   (pure VALU, full rate, zero DS traffic):
//     xor1 = update_dpp ctrl 0xB1 (perm [1,0,3,2])
//     xor2 = update_dpp ctrl 0x4E (perm [2,3,0,1])
//   Bit-exact same reduction tree ((p0+p1)+(p2+p3)). Everything else
//   byte-identical to R7 for a clean A/B. (R11 = R10 resubmitted, infra.)

#define B_    32
#define NSEG_ 8
#define S_    128
#define T_    1024
#define E_    256
#define HD_   128
#define G_    512   // 4*HD
#define K_    16

#define PIN4(v) asm volatile("" : "+v"((v).x), "+v"((v).y), "+v"((v).z), "+v"((v).w))

// Barrier that does NOT drain vmcnt: LDS writes made visible (lgkmcnt(0)),
// rendezvous, then a hard scheduling fence so following LDS reads can't
// hoist above the barrier (rule #18).
#define BAR_LDS() do {                                        \
    asm volatile("s_waitcnt lgkmcnt(0)" ::: "memory");        \
    __builtin_amdgcn_s_barrier();                             \
    __builtin_amdgcn_sched_barrier(0);                        \
} while (0)

// Quad-lane butterfly add via DPP (VALU pipe; __shfl_xor would be
// ds_bpermute on the shared DS pipe). CTRL: 0xB1 = lane^1, 0x4E = lane^2.
template <int CTRL>
__device__ __forceinline__ float qadd(float x) {
    int yi = __builtin_amdgcn_update_dpp(0, __float_as_int(x), CTRL, 0xF, 0xF, true);
    return x + __int_as_float(yi);
}

// ---------------- prep: seg offsets, fused+permuted bias, permuted Wih^T ----------------
// Gate-interleaved column n in [0,1024): dir=n>>9, j=(n>>2)&127, g=n&3
// maps to LSTM gate row (g*128+j) of direction dir.
__global__ void prep_kernel(const int* __restrict__ lengths,
                            int* __restrict__ seg_off, int* __restrict__ new_len,
                            const float* __restrict__ bih_f, const float* __restrict__ bhh_f,
                            const float* __restrict__ bih_b, const float* __restrict__ bhh_b,
                            float* __restrict__ bias1,
                            const float* __restrict__ Wih_f, const float* __restrict__ Wih_b,
                            float* __restrict__ WT1)
{
    int gtid = blockIdx.x * blockDim.x + threadIdx.x;
    if (gtid < B_) {
        int acc = 0;
        for (int s = 0; s < NSEG_; s++) { seg_off[gtid*NSEG_ + s] = acc; acc += lengths[gtid*NSEG_ + s]; }
        new_len[gtid] = acc;
    }
    if (gtid < 1024) {
        int n = gtid, dir = n >> 9, j = (n >> 2) & 127, g = n & 3;
        int row = g*128 + j;
        bias1[n] = dir ? (bih_b[row] + bhh_b[row]) : (bih_f[row] + bhh_f[row]);
    }
    // WT1[k][n] (256 x 1024): column n holds Wih row (g*128+j) of dir.
    for (int e = gtid; e < 256*1024; e += gridDim.x * blockDim.x) {
        int k = e >> 10, n = e & 1023;
        int dir = n >> 9, j = (n >> 2) & 127, g = n & 3;
        int row = g*128 + j;
        WT1[e] = dir ? Wih_b[row*E_ + k] : Wih_f[row*E_ + k];
    }
}

// ---------------- projection GEMM: xproj[b][p][n] = A[p][:] . WT1[:][n] + bias1[n] ----------------
template <int MODE>
__global__ void __launch_bounds__(256, 4)
proj_kernel(const int* __restrict__ texts, const float* __restrict__ emb,
            const float* __restrict__ WT1, const float* __restrict__ bias1,
            const float* __restrict__ lstm_packed, float* __restrict__ xproj,
            const int* __restrict__ seg_off, const int* __restrict__ new_len)
{
    int b  = blockIdx.z;
    int nl = new_len[b];
    int p0 = blockIdx.x * 32;
    if (p0 >= nl) return;
    int j0 = blockIdx.y * 256;

    __shared__ __align__(16) float As[32][256];
    __shared__ const float* rowp[32];
    int tid = threadIdx.x;
    if (tid < 32) {
        int p = p0 + tid;
        const float* r = emb;  // dummy row for invalid p
        if (p < nl) {
            if (MODE == 0) {
                int sg = 0;
                #pragma unroll
                for (int q = 1; q < NSEG_; q++) if (seg_off[b*NSEG_ + q] <= p) sg = q;
                int t   = p - seg_off[b*NSEG_ + sg];
                int tok = texts[(b*NSEG_ + sg)*S_ + t];
                r = emb + (size_t)tok * E_;
            } else {
                r = lstm_packed + ((size_t)b*T_ + p) * 256;
            }
        }
        rowp[tid] = r;
    }
    __syncthreads();
    #pragma unroll 4
    for (int i = 0; i < 32; i++) As[i][tid] = rowp[i][tid];
    __syncthreads();

    int pg = tid >> 6;
    int jg = tid & 63;
    int j  = j0 + jg*4;
    float acc[8][4];
    #pragma unroll
    for (int i = 0; i < 8; i++) { acc[i][0]=0.f; acc[i][1]=0.f; acc[i][2]=0.f; acc[i][3]=0.f; }

    const float* wbase = WT1 + j;
    for (int k = 0; k < 256; k += 4) {
        float4 w0 = *(const float4*)(wbase + (size_t)(k+0)*1024);
        float4 w1 = *(const float4*)(wbase + (size_t)(k+1)*1024);
        float4 w2 = *(const float4*)(wbase + (size_t)(k+2)*1024);
        float4 w3 = *(const float4*)(wbase + (size_t)(k+3)*1024);
        #pragma unroll
        for (int i = 0; i < 8; i++) {
            float4 a = *(const float4*)&As[pg*8 + i][k];
            acc[i][0] = fmaf(a.w, w3.x, fmaf(a.z, w2.x, fmaf(a.y, w1.x, fmaf(a.x, w0.x, acc[i][0]))));
            acc[i][1] = fmaf(a.w, w3.y, fmaf(a.z, w2.y, fmaf(a.y, w1.y, fmaf(a.x, w0.y, acc[i][1]))));
            acc[i][2] = fmaf(a.w, w3.z, fmaf(a.z, w2.z, fmaf(a.y, w1.z, fmaf(a.x, w0.z, acc[i][2]))));
            acc[i][3] = fmaf(a.w, w3.w, fmaf(a.z, w2.w, fmaf(a.y, w1.w, fmaf(a.x, w0.w, acc[i][3]))));
        }
    }
    float4 bs = *(const float4*)(bias1 + j);
    #pragma unroll
    for (int i = 0; i < 8; i++) {
        int p = p0 + pg*8 + i;
        if (p < nl) {
            float4 r;
            r.x = acc[i][0] + bs.x; r.y = acc[i][1] + bs.y;
            r.z = acc[i][2] + bs.z; r.w = acc[i][3] + bs.w;
            *(float4*)(xproj + (((size_t)b*T_ + p) << 10) + j) = r;
        }
    }
}

// ---------------- LSTM chain v8: in-wave K-slice reduction, DPP butterfly ----------------
__device__ __forceinline__ float sig_f(float x) { return 1.0f / (1.0f + __expf(-x)); }
__device__ __forceinline__ float tanh_f(float x) {
    float xc = fminf(fmaxf(x, -15.0f), 15.0f);
    float e  = __expf(-2.0f * xc);
    return (1.0f - e) / (1.0f + e);
}

// Thread t -> state j = t>>2, K-slice q = t&3 (4 adjacent lanes per state).
// h in LDS ping-pong, 4 pad-36 slices: slice s holds h[32s..32s+32) at
// float offset s*36 (read: 4 distinct addrs/instr, 16-lane broadcast each,
// banks 4q+4i distinct -> conflict-free).
__device__ __forceinline__ void lstm_chain(
    const float* __restrict__ Whh,     // [512][128] row-major, this dir
    const float* __restrict__ xp,      // xproj for this b: [1024][1024] gate-interleaved
    float* __restrict__ outp,          // lstm_packed for this b: [1024][256]
    int p_base, int len, int dir, int rev,
    const float* __restrict__ h0, const float* __restrict__ c0,
    float* __restrict__ hT, float* __restrict__ cT)
{
    __shared__ __align__(16) float h_sh[2][4*36];   // 2 x 144 floats
    int t = threadIdx.x;          // 0..511
    int j = t >> 2, q = t & 3;

    // Weights: gate rows j+128g, k in [32q,32q+32). Pinned (128 regs).
    float4 w[4][8];
    #pragma unroll
    for (int g = 0; g < 4; g++) {
        const float4* wr = (const float4*)(Whh + (size_t)(j + 128*g) * HD_ + 32*q);
        #pragma unroll
        for (int i = 0; i < 8; i++) { w[g][i] = wr[i]; PIN4(w[g][i]); }
    }

    float c_reg = c0 ? c0[j] : 0.0f;    // replicated across the 4 q-lanes
    if (q == 0) h_sh[0][(j >> 5)*36 + (j & 31)] = h0 ? h0[j] : 0.0f;

    // x-contribution: one float4 (gates i,f,g,o) per (p, j); 4 lanes share it.
    const float4* xc  = (const float4*)(xp + (size_t)dir * G_) + j;
    const int     oco = dir * HD_ + j;

    float4 xvc = make_float4(0.f,0.f,0.f,0.f), xvn = xvc;
    if (len > 0) xvc = xc[(size_t)(p_base + (rev ? len-1 : 0)) << 8];
    if (len > 1) xvn = xc[(size_t)(p_base + (rev ? len-2 : 1)) << 8];
    __syncthreads();

    for (int it = 0; it < len; it++) {
        int p_out = p_base + (rev ? (len-1-it) : it);
        // rotate xv pipeline; prefetch it+2 (consumed ~2 steps later)
        float4 xu = xvc; xvc = xvn;
        if (it + 2 < len) xvn = xc[(size_t)(p_base + (rev ? (len-3-it) : (it+2))) << 8];

        // matvec partial over k in [32q,32q+32) for all 4 gates of state j
        const float4* hv = (const float4*)(h_sh[it & 1] + q*36);
        float4 a0 = make_float4(0.f,0.f,0.f,0.f);
        float4 a1 = a0, a2 = a0, a3 = a0;
        #pragma unroll
        for (int i = 0; i < 8; i++) {
            float4 h4 = hv[i];
            a0.x = fmaf(h4.x, w[0][i].x, a0.x); a0.y = fmaf(h4.y, w[0][i].y, a0.y);
            a0.z = fmaf(h4.z, w[0][i].z, a0.z); a0.w = fmaf(h4.w, w[0][i].w, a0.w);
            a1.x = fmaf(h4.x, w[1][i].x, a1.x); a1.y = fmaf(h4.y, w[1][i].y, a1.y);
            a1.z = fmaf(h4.z, w[1][i].z, a1.z); a1.w = fmaf(h4.w, w[1][i].w, a1.w);
            a2.x = fmaf(h4.x, w[2][i].x, a2.x); a2.y = fmaf(h4.y, w[2][i].y, a2.y);
            a2.z = fmaf(h4.z, w[2][i].z, a2.z); a2.w = fmaf(h4.w, w[2][i].w, a2.w);
            a3.x = fmaf(h4.x, w[3][i].x, a3.x); a3.y = fmaf(h4.y, w[3][i].y, a3.y);
            a3.z = fmaf(h4.z, w[3][i].z, a3.z); a3.w = fmaf(h4.w, w[3][i].w, a3.w);
        }
        float4 part;
        part.x = (a0.x+a0.y)+(a0.z+a0.w);
        part.y = (a1.x+a1.y)+(a1.z+a1.w);
        part.z = (a2.x+a2.y)+(a2.z+a2.w);
        part.w = (a3.x+a3.y)+(a3.z+a3.w);
        // in-wave butterfly over the 4 q-lanes via DPP quad_perm (VALU pipe,
        // not ds_bpermute): (p0+p1)+(p2+p3), bit-exact
        part.x = qadd<0xB1>(part.x); part.y = qadd<0xB1>(part.y);
        part.z = qadd<0xB1>(part.z); part.w = qadd<0xB1>(part.w);
        part.x = qadd<0x4E>(part.x); part.y = qadd<0x4E>(part.y);
        part.z = qadd<0x4E>(part.z); part.w = qadd<0x4E>(part.w);

        // gate math, replicated on all 4 q-lanes (identical inputs)
        float gi = xu.x + part.x;
        float gf = xu.y + part.y;
        float gg = xu.z + part.z;
        float go = xu.w + part.w;
        float cn = sig_f(gf) * c_reg + sig_f(gi) * tanh_f(gg);
        c_reg = cn;
        float hn = sig_f(go) * tanh_f(cn);
        if (q == 0) {
            h_sh[(it+1) & 1][(j >> 5)*36 + (j & 31)] = hn;
            outp[(size_t)p_out * 256 + oco] = hn;   // fire-and-forget
        }
        BAR_LDS();
    }

    if (q == 0 && hT != nullptr) {
        hT[j] = h_sh[len & 1][(j >> 5)*36 + (j & 31)];
        cT[j] = c_reg;
    }
}

__global__ void __launch_bounds__(512, 2)
lstm1_kernel(const int* __restrict__ lengths, const int* __restrict__ seg_off,
             const float* __restrict__ Whh_f, const float* __restrict__ Whh_b,
             const float* __restrict__ xproj, float* __restrict__ lstm_packed,
             float* __restrict__ hinit, float* __restrict__ cinit)
{
    int cid = blockIdx.x;                 // 512 = 32b * 8seg * 2dir
    int b = cid >> 4, seg = (cid >> 1) & 7, dir = cid & 1;
    int len = lengths[b*NSEG_ + seg];
    int pb  = seg_off[b*NSEG_ + seg];
    const float* Whh = dir ? Whh_b : Whh_f;
    float* hT = nullptr; float* cT = nullptr;
    if (seg == NSEG_ - 1) {               // final states feed LSTM2 init
        hT = hinit + (dir*B_ + b)*HD_;
        cT = cinit + (dir*B_ + b)*HD_;
    }
    lstm_chain(Whh, xproj + ((size_t)b << 20), lstm_packed + (size_t)b*T_*256,
               pb, len, dir, dir, nullptr, nullptr, hT, cT);
}

__global__ void __launch_bounds__(512, 2)
lstm2_kernel(const int* __restrict__ new_len,
             const float* __restrict__ Whh_f, const float* __restrict__ Whh_b,
             const float* __restrict__ xproj, float* __restrict__ lstm_packed,
             const float* __restrict__ hinit, const float* __restrict__ cinit)
{
    int cid = blockIdx.x;                 // 64 = 32b * 2dir
    int b = cid >> 1, dir = cid & 1;
    int len = new_len[b];
    const float* Whh = dir ? Whh_b : Whh_f;
    lstm_chain(Whh, xproj + ((size_t)b << 20), lstm_packed + (size_t)b*T_*256,
               0, len, dir, dir,
               hinit + (dir*B_ + b)*HD_, cinit + (dir*B_ + b)*HD_,
               nullptr, nullptr);
}

// ---------------- emission: em[b][p][s] = lstm2[b][p][:] . Wlin[s][:] + blin[s] ----------------
__global__ void __launch_bounds__(256)
emission_kernel(const float* __restrict__ lstm_packed, const float* __restrict__ Wlin,
                const float* __restrict__ blin, float* __restrict__ emis,
                const int* __restrict__ new_len)
{
    int b  = blockIdx.y;
    int nl = new_len[b];
    int p0 = blockIdx.x * 16;
    if (p0 >= nl) return;
    int pl = threadIdx.x >> 4, s = threadIdx.x & 15;
    int p  = p0 + pl;
    const float4* xr = (const float4*)(lstm_packed + ((size_t)b*T_ + p) * 256);
    const float4* wr = (const float4*)(Wlin + (size_t)s * 256);
    float ax = 0.f, ay = 0.f, az = 0.f, aw = 0.f;
    #pragma unroll
    for (int i = 0; i < 64; i++) {
        float4 a = xr[i]; float4 ww = wr[i];
        ax = fmaf(a.x, ww.x, ax); ay = fmaf(a.y, ww.y, ay);
        az = fmaf(a.z, ww.z, az); aw = fmaf(a.w, ww.w, aw);
    }
    if (p < nl) emis[((size_t)b*T_ + p)*K_ + s] = (ax + ay) + (az + aw) + blin[s];
}

// ---------------- Viterbi: one block (1 wave) per batch element ----------------
__global__ void __launch_bounds__(64)
viterbi_kernel(const float* __restrict__ emis, const float* __restrict__ start,
               const float* __restrict__ trans, const float* __restrict__ endv,
               const int* __restrict__ new_len, float* __restrict__ out)
{
    int b    = blockIdx.x;
    int nl   = new_len[b];
    int lane = threadIdx.x;          // 64 lanes: 4 q-groups x 16 states
    int s    = lane & 15, q4 = lane >> 4;

    __shared__ unsigned char hist[T_ * K_];   // 16 KB
    __shared__ unsigned char tagb[T_];

    float tr[4];
    #pragma unroll
    for (int jj = 0; jj < 4; jj++) tr[jj] = trans[(q4*4 + jj)*K_ + s];

    const float* em = emis + (size_t)b * T_ * K_;
    float sc = start[s] + em[s];     // p = 0 (always valid)

    for (int p = 1; p < nl; p++) {
        float e = em[p*K_ + s];
        float m = -3.4e38f; int a = 0;
        #pragma unroll
        for (int jj = 0; jj < 4; jj++) {
            int q   = q4*4 + jj;
            float sq = __shfl(sc, q, 16);
            float v  = sq + tr[jj];
            if (v > m) { m = v; a = q; }
        }
        #pragma unroll
        for (int d = 16; d < 64; d <<= 1) {
            float mo = __shfl_xor(m, d);
            int   ao = __shfl_xor(a, d);
            if (mo > m || (mo == m && ao < a)) { m = mo; a = ao; }
        }
        sc = m + e;
        if (lane < K_) hist[p*K_ + s] = (unsigned char)a;
    }

    float m = sc + endv[s]; int a = s;
    #pragma unroll
    for (int d = 1; d < 16; d <<= 1) {
        float mo = __shfl_xor(m, d);
        int   ao = __shfl_xor(a, d);
        if (mo > m || (mo == m && ao < a)) { m = mo; a = ao; }
    }
    int last = a;
    if (lane == 0) out[T_*B_ + b] = m;
    __syncthreads();

    for (int i = lane; i < T_; i += 64) tagb[i] = (unsigned char)last;
    __syncthreads();
    if (lane == 0) {
        int cur = last;
        for (int j = nl - 2; j >= 0; j--) {
            cur = hist[(j+1)*K_ + cur];
            tagb[j] = (unsigned char)cur;
        }
    }
    __syncthreads();
    for (int i = lane; i < T_; i += 64) out[(size_t)i*B_ + b] = (float)tagb[i];
}

// ---------------- host ----------------
extern "C" void kernel_launch(void* const* d_in, const int* in_sizes, int n_in,
                              void* d_out, int out_size, void* d_ws, size_t ws_size,
                              hipStream_t stream)
{
    (void)in_sizes; (void)n_in; (void)out_size; (void)ws_size;
    const int*   texts   = (const int*)  d_in[0];
    const int*   lengths = (const int*)  d_in[1];
    const float* emb     = (const float*)d_in[2];
    const float* Wih_f   = (const float*)d_in[3];
    const float* Whh_f   = (const float*)d_in[4];
    const float* bih_f   = (const float*)d_in[5];
    const float* bhh_f   = (const float*)d_in[6];
    const float* Wih_b   = (const float*)d_in[7];
    const float* Whh_b   = (const float*)d_in[8];
    const float* bih_b   = (const float*)d_in[9];
    const float* bhh_b   = (const float*)d_in[10];
    const float* Wlin    = (const float*)d_in[11];
    const float* blin    = (const float*)d_in[12];
    const float* c_start = (const float*)d_in[13];
    const float* c_trans = (const float*)d_in[14];
    const float* c_end   = (const float*)d_in[15];
    float* out = (float*)d_out;

    // workspace carve (~163 MB total, all 16B-aligned)
    char* w = (char*)d_ws;
    int*   seg_off     = (int*)(w);                      // 256 ints
    int*   new_len     = (int*)(w + 1024);               // 32 ints
    float* bias1       = (float*)(w + 4096);             // 1024 f
    float* WT1         = (float*)(w + 8192);             // 262144 f (1 MB)
    float* hinit       = (float*)(w + 8192 + 1048576);   // 8192 f
    float* cinit       = hinit + 8192;                   // 8192 f
    float* lstm_packed = cinit + 8192;                   // 32*1024*256 f (32 MB)
    float* xproj       = lstm_packed + (size_t)B_*T_*256;    // 32*1024*1024 f (128 MB)
    float* emis        = xproj + ((size_t)B_ << 20);         // 32*1024*16 f (2 MB)

    prep_kernel<<<128, 256, 0, stream>>>(lengths, seg_off, new_len,
                                         bih_f, bhh_f, bih_b, bhh_b, bias1,
                                         Wih_f, Wih_b, WT1);
    proj_kernel<0><<<dim3(32, 4, B_), 256, 0, stream>>>(texts, emb, WT1, bias1,
                                                        lstm_packed, xproj, seg_off, new_len);
    lstm1_kernel<<<512, 512, 0, stream>>>(lengths, seg_off, Whh_f, Whh_b,
                                          xproj, lstm_packed, hinit, cinit);
    proj_kernel<1><<<dim3(32, 4, B_), 256, 0, stream>>>(texts, emb, WT1, bias1,
                                                        lstm_packed, xproj, seg_off, new_len);
    lstm2_kernel<<<64, 512, 0, stream>>>(new_len, Whh_f, Whh_b,
                                         xproj, lstm_packed, hinit, cinit);
    emission_kernel<<<dim3(64, B_), 256, 0, stream>>>(lstm_packed, Wlin, blin, emis, new_len);
    viterbi_kernel<<<B_, 64, 0, stream>>>(emis, c_start, c_trans, c_end, new_len, out);
}

// Round 9
// 1587.945 us; speedup vs baseline: 1.1329x; 1.1188x over previous
//
#include <hip/hip_runtime.h>
#include <cstdint>
#include <cstddef>

// BiLSTM-CRF forward, MI355X fp32 implementation.
// Pipeline: prep -> proj1(emb gather GEMM) -> lstm1(512 chains) -> proj2
//           -> lstm2(64 chains) -> emission -> viterbi(+backtrace).
//
// R12: RESTORE R5 (best measured: 1586.6us total, lstm2 597us).
//   Closed branches, each with two corroborating measurements:
//   - R6 chain pairing (800us lstm2): dispatch bound by LONGEST chain's
//     serial step count; pairing only helps aggregate throughput.
//   - R7/R10 in-wave K-slice reduce (763us lstm2, shfl and DPP identical):
//     replicating gate/xv/loop scaffolding on all 512 threads adds ~900
//     issue-cyc/step/CU -- more than the saved psum LDS round-trips.
//   - Register wall: one direction's Whh = 64K floats ~= the per-CU
//     register file share -> exactly ONE chain per CU; no co-residency.
//   R5 structure: 512-thread block, j=t&127 / q=t>>7 (wave-uniform q ->
//   h reads are pure LDS broadcast), weights pinned 128 regs/thread,
//   psum LDS handoff, 2-wave reducer, raw lgkm-only barriers (BAR_LDS,
//   never drains vmcnt), KS_=8 grouped global access (hn flush + xv
//   burst at group top), gate-interleaved xproj (one float4/step/j).

#define B_    32
#define NSEG_ 8
#define S_    128
#define T_    1024
#define E_    256
#define HD_   128
#define G_    512   // 4*HD
#define K_    16
#define KS_   8     // steps per group (global-drain amortization)

#define PIN4(v) asm volatile("" : "+v"((v).x), "+v"((v).y), "+v"((v).z), "+v"((v).w))

// Barrier that does NOT drain vmcnt: LDS writes made visible (lgkmcnt(0)),
// rendezvous, then a hard scheduling fence so following LDS reads can't
// hoist above the barrier (rule #18).
#define BAR_LDS() do {                                        \
    asm volatile("s_waitcnt lgkmcnt(0)" ::: "memory");        \
    __builtin_amdgcn_s_barrier();                             \
    __builtin_amdgcn_sched_barrier(0);                        \
} while (0)

// ---------------- prep: seg offsets, fused+permuted bias, permuted Wih^T ----------------
// Gate-interleaved column n in [0,1024): dir=n>>9, j=(n>>2)&127, g=n&3
// maps to LSTM gate row (g*128+j) of direction dir.
__global__ void prep_kernel(const int* __restrict__ lengths,
                            int* __restrict__ seg_off, int* __restrict__ new_len,
                            const float* __restrict__ bih_f, const float* __restrict__ bhh_f,
                            const float* __restrict__ bih_b, const float* __restrict__ bhh_b,
                            float* __restrict__ bias1,
                            const float* __restrict__ Wih_f, const float* __restrict__ Wih_b,
                            float* __restrict__ WT1)
{
    int gtid = blockIdx.x * blockDim.x + threadIdx.x;
    if (gtid < B_) {
        int acc = 0;
        for (int s = 0; s < NSEG_; s++) { seg_off[gtid*NSEG_ + s] = acc; acc += lengths[gtid*NSEG_ + s]; }
        new_len[gtid] = acc;
    }
    if (gtid < 1024) {
        int n = gtid, dir = n >> 9, j = (n >> 2) & 127, g = n & 3;
        int row = g*128 + j;
        bias1[n] = dir ? (bih_b[row] + bhh_b[row]) : (bih_f[row] + bhh_f[row]);
    }
    // WT1[k][n] (256 x 1024): column n holds Wih row (g*128+j) of dir.
    for (int e = gtid; e < 256*1024; e += gridDim.x * blockDim.x) {
        int k = e >> 10, n = e & 1023;
        int dir = n >> 9, j = (n >> 2) & 127, g = n & 3;
        int row = g*128 + j;
        WT1[e] = dir ? Wih_b[row*E_ + k] : Wih_f[row*E_ + k];
    }
}

// ---------------- projection GEMM: xproj[b][p][n] = A[p][:] . WT1[:][n] + bias1[n] ----------------
template <int MODE>
__global__ void __launch_bounds__(256, 4)
proj_kernel(const int* __restrict__ texts, const float* __restrict__ emb,
            const float* __restrict__ WT1, const float* __restrict__ bias1,
            const float* __restrict__ lstm_packed, float* __restrict__ xproj,
            const int* __restrict__ seg_off, const int* __restrict__ new_len)
{
    int b  = blockIdx.z;
    int nl = new_len[b];
    int p0 = blockIdx.x * 32;
    if (p0 >= nl) return;
    int j0 = blockIdx.y * 256;

    __shared__ __align__(16) float As[32][256];
    __shared__ const float* rowp[32];
    int tid = threadIdx.x;
    if (tid < 32) {
        int p = p0 + tid;
        const float* r = emb;  // dummy row for invalid p
        if (p < nl) {
            if (MODE == 0) {
                int sg = 0;
                #pragma unroll
                for (int q = 1; q < NSEG_; q++) if (seg_off[b*NSEG_ + q] <= p) sg = q;
                int t   = p - seg_off[b*NSEG_ + sg];
                int tok = texts[(b*NSEG_ + sg)*S_ + t];
                r = emb + (size_t)tok * E_;
            } else {
                r = lstm_packed + ((size_t)b*T_ + p) * 256;
            }
        }
        rowp[tid] = r;
    }
    __syncthreads();
    #pragma unroll 4
    for (int i = 0; i < 32; i++) As[i][tid] = rowp[i][tid];
    __syncthreads();

    int pg = tid >> 6;
    int jg = tid & 63;
    int j  = j0 + jg*4;
    float acc[8][4];
    #pragma unroll
    for (int i = 0; i < 8; i++) { acc[i][0]=0.f; acc[i][1]=0.f; acc[i][2]=0.f; acc[i][3]=0.f; }

    const float* wbase = WT1 + j;
    for (int k = 0; k < 256; k += 4) {
        float4 w0 = *(const float4*)(wbase + (size_t)(k+0)*1024);
        float4 w1 = *(const float4*)(wbase + (size_t)(k+1)*1024);
        float4 w2 = *(const float4*)(wbase + (size_t)(k+2)*1024);
        float4 w3 = *(const float4*)(wbase + (size_t)(k+3)*1024);
        #pragma unroll
        for (int i = 0; i < 8; i++) {
            float4 a = *(const float4*)&As[pg*8 + i][k];
            acc[i][0] = fmaf(a.w, w3.x, fmaf(a.z, w2.x, fmaf(a.y, w1.x, fmaf(a.x, w0.x, acc[i][0]))));
            acc[i][1] = fmaf(a.w, w3.y, fmaf(a.z, w2.y, fmaf(a.y, w1.y, fmaf(a.x, w0.y, acc[i][1]))));
            acc[i][2] = fmaf(a.w, w3.z, fmaf(a.z, w2.z, fmaf(a.y, w1.z, fmaf(a.x, w0.z, acc[i][2]))));
            acc[i][3] = fmaf(a.w, w3.w, fmaf(a.z, w2.w, fmaf(a.y, w1.w, fmaf(a.x, w0.w, acc[i][3]))));
        }
    }
    float4 bs = *(const float4*)(bias1 + j);
    #pragma unroll
    for (int i = 0; i < 8; i++) {
        int p = p0 + pg*8 + i;
        if (p < nl) {
            float4 r;
            r.x = acc[i][0] + bs.x; r.y = acc[i][1] + bs.y;
            r.z = acc[i][2] + bs.z; r.w = acc[i][3] + bs.w;
            *(float4*)(xproj + (((size_t)b*T_ + p) << 10) + j) = r;
        }
    }
}

// ---------------- LSTM chain (R5): K-grouped float4 gate loads + vmcnt-preserving barriers ----------------
__device__ __forceinline__ float sig_f(float x) { return 1.0f / (1.0f + __expf(-x)); }
__device__ __forceinline__ float tanh_f(float x) {
    float xc = fminf(fmaxf(x, -15.0f), 15.0f);
    float e  = __expf(-2.0f * xc);
    return (1.0f - e) / (1.0f + e);
}

__device__ __forceinline__ void lstm_chain(
    const float* __restrict__ Whh,     // [512][128] row-major, this dir
    const float* __restrict__ xp,      // xproj for this b: [1024][1024] gate-interleaved, bias folded
    float* __restrict__ outp,          // lstm_packed for this b: [1024][256]
    int p_base, int len, int dir, int rev,
    const float* __restrict__ h0, const float* __restrict__ c0,
    float* __restrict__ hT, float* __restrict__ cT)
{
    __shared__ __align__(16) float  h_sh[HD_];
    __shared__ __align__(16) float4 psum[4*HD_];   // [q][j], conflict-free lane order
    int t = threadIdx.x;          // 0..511
    int j = t & 127, q = t >> 7;  // per-wave q is uniform -> h reads are pure broadcast

    // Weights: gate rows j+128g, k in [32q, 32q+32). Pinned into regs (128/thread).
    float4 w[4][8];
    #pragma unroll
    for (int g = 0; g < 4; g++) {
        const float4* wr = (const float4*)(Whh + (size_t)(j + 128*g) * HD_ + 32*q);
        #pragma unroll
        for (int i = 0; i < 8; i++) { w[g][i] = wr[i]; PIN4(w[g][i]); }
    }

    float c_reg = 0.0f;
    if (t < HD_) {
        h_sh[t] = h0 ? h0[t] : 0.0f;
        c_reg   = c0 ? c0[t] : 0.0f;
    }
    __syncthreads();   // once; also drains h0/c0 loads — fine

    // x-contribution: one float4 per (p, j): gates i,f,g,o at n = dir*512 + j*4 + {0..3}
    const float4* xcol4 = (const float4*)(xp + (size_t)dir * G_) + j;
    const int     oco   = dir * HD_ + j;

    float4 xv[KS_];
    float  hbuf[KS_];

    for (int gs = 0; gs < len; gs += KS_) {
        // ---- group prologue: the ONLY global traffic. With BAR_LDS inner
        // barriers these loads/stores stay in flight across steps; the
        // compiler waits per-use with counted vmcnt instead of vmcnt(0).
        if (t < HD_) {
            if (gs > 0) {
                #pragma unroll
                for (int u = 0; u < KS_; u++) {          // prev group always full
                    int s = gs - KS_ + u;
                    int p = p_base + (rev ? (len - 1 - s) : s);
                    outp[(size_t)p * 256 + oco] = hbuf[u];
                }
            }
            #pragma unroll
            for (int u = 0; u < KS_; u++) {
                int s = gs + u;
                if (s < len) {
                    int p = p_base + (rev ? (len - 1 - s) : s);
                    xv[u] = xcol4[(size_t)p << 8];       // p*1024 floats = p*256 float4
                }
            }
        }
        // ---- 8 steps; barriers drain LDS only (no vmcnt(0)) ----
        #pragma unroll
        for (int u = 0; u < KS_; u++) {
            if (gs + u < len) {                          // block-uniform predicate
                const float4* hv = (const float4*)h_sh + q * 8;
                float4 a0 = make_float4(0.f,0.f,0.f,0.f);
                float4 a1 = a0, a2 = a0, a3 = a0;
                #pragma unroll
                for (int i = 0; i < 8; i++) {
                    float4 h4 = hv[i];
                    a0.x = fmaf(h4.x, w[0][i].x, a0.x); a0.y = fmaf(h4.y, w[0][i].y, a0.y);
                    a0.z = fmaf(h4.z, w[0][i].z, a0.z); a0.w = fmaf(h4.w, w[0][i].w, a0.w);
                    a1.x = fmaf(h4.x, w[1][i].x, a1.x); a1.y = fmaf(h4.y, w[1][i].y, a1.y);
                    a1.z = fmaf(h4.z, w[1][i].z, a1.z); a1.w = fmaf(h4.w, w[1][i].w, a1.w);
                    a2.x = fmaf(h4.x, w[2][i].x, a2.x); a2.y = fmaf(h4.y, w[2][i].y, a2.y);
                    a2.z = fmaf(h4.z, w[2][i].z, a2.z); a2.w = fmaf(h4.w, w[2][i].w, a2.w);
                    a3.x = fmaf(h4.x, w[3][i].x, a3.x); a3.y = fmaf(h4.y, w[3][i].y, a3.y);
                    a3.z = fmaf(h4.z, w[3][i].z, a3.z); a3.w = fmaf(h4.w, w[3][i].w, a3.w);
                }
                psum[q*128 + j] = make_float4((a0.x+a0.y)+(a0.z+a0.w),
                                              (a1.x+a1.y)+(a1.z+a1.w),
                                              (a2.x+a2.y)+(a2.z+a2.w),
                                              (a3.x+a3.y)+(a3.z+a3.w));
                BAR_LDS();
                if (t < HD_) {
                    float4 p0 = psum[j], p1 = psum[128 + j], p2 = psum[256 + j], p3 = psum[384 + j];
                    float gi = xv[u].x + ((p0.x + p1.x) + (p2.x + p3.x));
                    float gf = xv[u].y + ((p0.y + p1.y) + (p2.y + p3.y));
                    float gg = xv[u].z + ((p0.z + p1.z) + (p2.z + p3.z));
                    float go = xv[u].w + ((p0.w + p1.w) + (p2.w + p3.w));
                    float cn = sig_f(gf) * c_reg + sig_f(gi) * tanh_f(gg);
                    c_reg = cn;
                    float hn = sig_f(go) * tanh_f(cn);
                    h_sh[j] = hn;
                    hbuf[u] = hn;
                }
                BAR_LDS();
            }
        }
    }
    // final flush of the last (possibly partial) group
    if (t < HD_ && len > 0) {
        int gs = ((len - 1) / KS_) * KS_;
        #pragma unroll
        for (int u = 0; u < KS_; u++) {
            int s = gs + u;
            if (s < len) {
                int p = p_base + (rev ? (len - 1 - s) : s);
                outp[(size_t)p * 256 + oco] = hbuf[u];
            }
        }
    }
    if (hT != nullptr && t < HD_) { hT[t] = h_sh[t]; cT[t] = c_reg; }
}

__global__ void __launch_bounds__(512, 1)
lstm1_kernel(const int* __restrict__ lengths, const int* __restrict__ seg_off,
             const float* __restrict__ Whh_f, const float* __restrict__ Whh_b,
             const float* __restrict__ xproj, float* __restrict__ lstm_packed,
             float* __restrict__ hinit, float* __restrict__ cinit)
{
    int cid = blockIdx.x;                 // 512 = 32b * 8seg * 2dir
    int b = cid >> 4, seg = (cid >> 1) & 7, dir = cid & 1;
    int len = lengths[b*NSEG_ + seg];
    int pb  = seg_off[b*NSEG_ + seg];
    const float* Whh = dir ? Whh_b : Whh_f;
    float* hT = nullptr; float* cT = nullptr;
    if (seg == NSEG_ - 1) {               // final states feed LSTM2 init
        hT = hinit + (dir*B_ + b)*HD_;
        cT = cinit + (dir*B_ + b)*HD_;
    }
    lstm_chain(Whh, xproj + ((size_t)b << 20), lstm_packed + (size_t)b*T_*256,
               pb, len, dir, dir, nullptr, nullptr, hT, cT);
}

__global__ void __launch_bounds__(512, 1)
lstm2_kernel(const int* __restrict__ new_len,
             const float* __restrict__ Whh_f, const float* __restrict__ Whh_b,
             const float* __restrict__ xproj, float* __restrict__ lstm_packed,
             const float* __restrict__ hinit, const float* __restrict__ cinit)
{
    int cid = blockIdx.x;                 // 64 = 32b * 2dir
    int b = cid >> 1, dir = cid & 1;
    int len = new_len[b];
    const float* Whh = dir ? Whh_b : Whh_f;
    lstm_chain(Whh, xproj + ((size_t)b << 20), lstm_packed + (size_t)b*T_*256,
               0, len, dir, dir,
               hinit + (dir*B_ + b)*HD_, cinit + (dir*B_ + b)*HD_,
               nullptr, nullptr);
}

// ---------------- emission: em[b][p][s] = lstm2[b][p][:] . Wlin[s][:] + blin[s] ----------------
__global__ void __launch_bounds__(256)
emission_kernel(const float* __restrict__ lstm_packed, const float* __restrict__ Wlin,
                const float* __restrict__ blin, float* __restrict__ emis,
                const int* __restrict__ new_len)
{
    int b  = blockIdx.y;
    int nl = new_len[b];
    int p0 = blockIdx.x * 16;
    if (p0 >= nl) return;
    int pl = threadIdx.x >> 4, s = threadIdx.x & 15;
    int p  = p0 + pl;
    const float4* xr = (const float4*)(lstm_packed + ((size_t)b*T_ + p) * 256);
    const float4* wr = (const float4*)(Wlin + (size_t)s * 256);
    float ax = 0.f, ay = 0.f, az = 0.f, aw = 0.f;
    #pragma unroll
    for (int i = 0; i < 64; i++) {
        float4 a = xr[i]; float4 ww = wr[i];
        ax = fmaf(a.x, ww.x, ax); ay = fmaf(a.y, ww.y, ay);
        az = fmaf(a.z, ww.z, az); aw = fmaf(a.w, ww.w, aw);
    }
    if (p < nl) emis[((size_t)b*T_ + p)*K_ + s] = (ax + ay) + (az + aw) + blin[s];
}

// ---------------- Viterbi: one block (1 wave) per batch element ----------------
__global__ void __launch_bounds__(64)
viterbi_kernel(const float* __restrict__ emis, const float* __restrict__ start,
               const float* __restrict__ trans, const float* __restrict__ endv,
               const int* __restrict__ new_len, float* __restrict__ out)
{
    int b    = blockIdx.x;
    int nl   = new_len[b];
    int lane = threadIdx.x;          // 64 lanes: 4 q-groups x 16 states
    int s    = lane & 15, q4 = lane >> 4;

    __shared__ unsigned char hist[T_ * K_];   // 16 KB
    __shared__ unsigned char tagb[T_];

    float tr[4];
    #pragma unroll
    for (int jj = 0; jj < 4; jj++) tr[jj] = trans[(q4*4 + jj)*K_ + s];

    const float* em = emis + (size_t)b * T_ * K_;
    float sc = start[s] + em[s];     // p = 0 (always valid)

    for (int p = 1; p < nl; p++) {
        float e = em[p*K_ + s];
        float m = -3.4e38f; int a = 0;
        #pragma unroll
        for (int jj = 0; jj < 4; jj++) {
            int q   = q4*4 + jj;
            float sq = __shfl(sc, q, 16);
            float v  = sq + tr[jj];
            if (v > m) { m = v; a = q; }
        }
        #pragma unroll
        for (int d = 16; d < 64; d <<= 1) {
            float mo = __shfl_xor(m, d);
            int   ao = __shfl_xor(a, d);
            if (mo > m || (mo == m && ao < a)) { m = mo; a = ao; }
        }
        sc = m + e;
        if (lane < K_) hist[p*K_ + s] = (unsigned char)a;
    }

    float m = sc + endv[s]; int a = s;
    #pragma unroll
    for (int d = 1; d < 16; d <<= 1) {
        float mo = __shfl_xor(m, d);
        int   ao = __shfl_xor(a, d);
        if (mo > m || (mo == m && ao < a)) { m = mo; a = ao; }
    }
    int last = a;
    if (lane == 0) out[T_*B_ + b] = m;
    __syncthreads();

    for (int i = lane; i < T_; i += 64) tagb[i] = (unsigned char)last;
    __syncthreads();
    if (lane == 0) {
        int cur = last;
        for (int j = nl - 2; j >= 0; j--) {
            cur = hist[(j+1)*K_ + cur];
            tagb[j] = (unsigned char)cur;
        }
    }
    __syncthreads();
    for (int i = lane; i < T_; i += 64) out[(size_t)i*B_ + b] = (float)tagb[i];
}

// ---------------- host ----------------
extern "C" void kernel_launch(void* const* d_in, const int* in_sizes, int n_in,
                              void* d_out, int out_size, void* d_ws, size_t ws_size,
                              hipStream_t stream)
{
    (void)in_sizes; (void)n_in; (void)out_size; (void)ws_size;
    const int*   texts   = (const int*)  d_in[0];
    const int*   lengths = (const int*)  d_in[1];
    const float* emb     = (const float*)d_in[2];
    const float* Wih_f   = (const float*)d_in[3];
    const float* Whh_f   = (const float*)d_in[4];
    const float* bih_f   = (const float*)d_in[5];
    const float* bhh_f   = (const float*)d_in[6];
    const float* Wih_b   = (const float*)d_in[7];
    const float* Whh_b   = (const float*)d_in[8];
    const float* bih_b   = (const float*)d_in[9];
    const float* bhh_b   = (const float*)d_in[10];
    const float* Wlin    = (const float*)d_in[11];
    const float* blin    = (const float*)d_in[12];
    const float* c_start = (const float*)d_in[13];
    const float* c_trans = (const float*)d_in[14];
    const float* c_end   = (const float*)d_in[15];
    float* out = (float*)d_out;

    // workspace carve (~163 MB total, all 16B-aligned)
    char* w = (char*)d_ws;
    int*   seg_off     = (int*)(w);                      // 256 ints
    int*   new_len     = (int*)(w + 1024);               // 32 ints
    float* bias1       = (float*)(w + 4096);             // 1024 f
    float* WT1         = (float*)(w + 8192);             // 262144 f (1 MB)
    float* hinit       = (float*)(w + 8192 + 1048576);   // 8192 f
    float* cinit       = hinit + 8192;                   // 8192 f
    float* lstm_packed = cinit + 8192;                   // 32*1024*256 f (32 MB)
    float* xproj       = lstm_packed + (size_t)B_*T_*256;    // 32*1024*1024 f (128 MB)
    float* emis        = xproj + ((size_t)B_ << 20);         // 32*1024*16 f (2 MB)

    prep_kernel<<<128, 256, 0, stream>>>(lengths, seg_off, new_len,
                                         bih_f, bhh_f, bih_b, bhh_b, bias1,
                                         Wih_f, Wih_b, WT1);
    proj_kernel<0><<<dim3(32, 4, B_), 256, 0, stream>>>(texts, emb, WT1, bias1,
                                                        lstm_packed, xproj, seg_off, new_len);
    lstm1_kernel<<<512, 512, 0, stream>>>(lengths, seg_off, Whh_f, Whh_b,
                                          xproj, lstm_packed, hinit, cinit);
    proj_kernel<1><<<dim3(32, 4, B_), 256, 0, stream>>>(texts, emb, WT1, bias1,
                                                        lstm_packed, xproj, seg_off, new_len);
    lstm2_kernel<<<64, 512, 0, stream>>>(new_len, Whh_f, Whh_b,
                                         xproj, lstm_packed, hinit, cinit);
    emission_kernel<<<dim3(64, B_), 256, 0, stream>>>(lstm_packed, Wlin, blin, emis, new_len);
    viterbi_kernel<<<B_, 64, 0, stream>>>(emis, c_start, c_trans, c_end, new_len, out);
}

// Round 10
// 1562.081 us; speedup vs baseline: 1.1517x; 1.0166x over previous
//
#include <hip/hip_runtime.h>
#include <cstdint>
#include <cstddef>

// BiLSTM-CRF forward, MI355X fp32 implementation.
// Pipeline: prep -> proj1(emb gather GEMM) -> lstm1(512 chains, LPT order)
//           -> proj2 -> lstm2(64 chains) -> emission -> viterbi(+backtrace).
//
// R12 anchor (reproduced 1587.9us; lstm2 599.7): R5 LSTM structure frozen —
//   it sits at a register wall (120 VGPR + 128 AGPR = 248/wave, 2 waves/SIMD,
//   8 spare regs) with a forced 2-barrier serial step. Closed branches:
//   pairing (longest-chain-bound), in-wave reduce (replication tax).
// R13 (this round), lstm2 untouched:
//   (a) proj retile: 8 rows x 8 cols per thread (tile 32x512, grid (32,2,B)).
//       FMA per k4 doubles (128->256) at constant 8 As-broadcasts -> LDS-pipe
//       instr per FLOP halves; As staging duplicated 2x not 4x. Per-output
//       k-summation order IDENTICAL (same nested fmaf chain, k ascending).
//   (b) lstm1 LPT: blocks pick chains via a longest-first rank-sort (built in
//       prep). HW launches blocks in ID order as CUs free -> LPT makespan
//       ~140-150 steps vs random ~190+. Pure block->chain permutation.

#define B_    32
#define NSEG_ 8
#define S_    128
#define T_    1024
#define E_    256
#define HD_   128
#define G_    512   // 4*HD
#define K_    16
#define KS_   8     // steps per group (global-drain amortization)

#define PIN4(v) asm volatile("" : "+v"((v).x), "+v"((v).y), "+v"((v).z), "+v"((v).w))

// Barrier that does NOT drain vmcnt: LDS writes made visible (lgkmcnt(0)),
// rendezvous, then a hard scheduling fence so following LDS reads can't
// hoist above the barrier (rule #18).
#define BAR_LDS() do {                                        \
    asm volatile("s_waitcnt lgkmcnt(0)" ::: "memory");        \
    __builtin_amdgcn_s_barrier();                             \
    __builtin_amdgcn_sched_barrier(0);                        \
} while (0)

// ---------------- prep: seg offsets, fused+permuted bias, permuted Wih^T, LPT order ----------------
// Gate-interleaved column n in [0,1024): dir=n>>9, j=(n>>2)&127, g=n&3
// maps to LSTM gate row (g*128+j) of direction dir.
__global__ void prep_kernel(const int* __restrict__ lengths,
                            int* __restrict__ seg_off, int* __restrict__ new_len,
                            int* __restrict__ order1,
                            const float* __restrict__ bih_f, const float* __restrict__ bhh_f,
                            const float* __restrict__ bih_b, const float* __restrict__ bhh_b,
                            float* __restrict__ bias1,
                            const float* __restrict__ Wih_f, const float* __restrict__ Wih_b,
                            float* __restrict__ WT1)
{
    __shared__ int s_len[256];
    __shared__ int s_ord[256];
    int gtid = blockIdx.x * blockDim.x + threadIdx.x;
    if (gtid < B_) {
        int acc = 0;
        for (int s = 0; s < NSEG_; s++) { seg_off[gtid*NSEG_ + s] = acc; acc += lengths[gtid*NSEG_ + s]; }
        new_len[gtid] = acc;
    }
    if (gtid < 1024) {
        int n = gtid, dir = n >> 9, j = (n >> 2) & 127, g = n & 3;
        int row = g*128 + j;
        bias1[n] = dir ? (bih_b[row] + bhh_b[row]) : (bih_f[row] + bhh_f[row]);
    }
    // LPT order over the 256 (b,seg) chains (both dirs share a length):
    // rank-sort by length desc (index asc tiebreak) -> order1[rank] = b*8+seg.
    if (blockIdx.x == 0) {
        int t = threadIdx.x;              // 0..255
        s_len[t] = lengths[t];
        __syncthreads();
        int my = s_len[t], rank = 0;
        for (int u = 0; u < 256; u++) {
            int lu = s_len[u];
            if (lu > my || (lu == my && u < t)) rank++;
        }
        s_ord[rank] = t;
        __syncthreads();
        order1[t] = s_ord[t];
    }
    // WT1[k][n] (256 x 1024): column n holds Wih row (g*128+j) of dir.
    for (int e = gtid; e < 256*1024; e += gridDim.x * blockDim.x) {
        int k = e >> 10, n = e & 1023;
        int dir = n >> 9, j = (n >> 2) & 127, g = n & 3;
        int row = g*128 + j;
        WT1[e] = dir ? Wih_b[row*E_ + k] : Wih_f[row*E_ + k];
    }
}

// ---------------- projection GEMM: xproj[b][p][n] = A[p][:] . WT1[:][n] + bias1[n] ----------------
// R13 tile: 32 rows x 512 cols per block; thread = 8 rows x 8 cols.
// Per-output k-chain identical to the 8x4 version (bit-exact).
template <int MODE>
__global__ void __launch_bounds__(256, 2)
proj_kernel(const int* __restrict__ texts, const float* __restrict__ emb,
            const float* __restrict__ WT1, const float* __restrict__ bias1,
            const float* __restrict__ lstm_packed, float* __restrict__ xproj,
            const int* __restrict__ seg_off, const int* __restrict__ new_len)
{
    int b  = blockIdx.z;
    int nl = new_len[b];
    int p0 = blockIdx.x * 32;
    if (p0 >= nl) return;
    int j0 = blockIdx.y * 512;

    __shared__ __align__(16) float As[32][256];
    __shared__ const float* rowp[32];
    int tid = threadIdx.x;
    if (tid < 32) {
        int p = p0 + tid;
        const float* r = emb;  // dummy row for invalid p
        if (p < nl) {
            if (MODE == 0) {
                int sg = 0;
                #pragma unroll
                for (int q = 1; q < NSEG_; q++) if (seg_off[b*NSEG_ + q] <= p) sg = q;
                int t   = p - seg_off[b*NSEG_ + sg];
                int tok = texts[(b*NSEG_ + sg)*S_ + t];
                r = emb + (size_t)tok * E_;
            } else {
                r = lstm_packed + ((size_t)b*T_ + p) * 256;
            }
        }
        rowp[tid] = r;
    }
    __syncthreads();
    #pragma unroll 4
    for (int i = 0; i < 32; i++) As[i][tid] = rowp[i][tid];
    __syncthreads();

    int pg = tid >> 6;        // 0..3 -> rows pg*8 .. +7
    int jg = tid & 63;        // cols j0 + jg*8 .. +7
    int j  = j0 + jg*8;
    float acc[8][8];
    #pragma unroll
    for (int i = 0; i < 8; i++)
        #pragma unroll
        for (int c = 0; c < 8; c++) acc[i][c] = 0.f;

    const float* wbase = WT1 + j;
    for (int k = 0; k < 256; k += 4) {
        float4 w00 = *(const float4*)(wbase + (size_t)(k+0)*1024);
        float4 w01 = *(const float4*)(wbase + (size_t)(k+0)*1024 + 4);
        float4 w10 = *(const float4*)(wbase + (size_t)(k+1)*1024);
        float4 w11 = *(const float4*)(wbase + (size_t)(k+1)*1024 + 4);
        float4 w20 = *(const float4*)(wbase + (size_t)(k+2)*1024);
        float4 w21 = *(const float4*)(wbase + (size_t)(k+2)*1024 + 4);
        float4 w30 = *(const float4*)(wbase + (size_t)(k+3)*1024);
        float4 w31 = *(const float4*)(wbase + (size_t)(k+3)*1024 + 4);
        #pragma unroll
        for (int i = 0; i < 8; i++) {
            float4 a = *(const float4*)&As[pg*8 + i][k];
            acc[i][0] = fmaf(a.w, w30.x, fmaf(a.z, w20.x, fmaf(a.y, w10.x, fmaf(a.x, w00.x, acc[i][0]))));
            acc[i][1] = fmaf(a.w, w30.y, fmaf(a.z, w20.y, fmaf(a.y, w10.y, fmaf(a.x, w00.y, acc[i][1]))));
            acc[i][2] = fmaf(a.w, w30.z, fmaf(a.z, w20.z, fmaf(a.y, w10.z, fmaf(a.x, w00.z, acc[i][2]))));
            acc[i][3] = fmaf(a.w, w30.w, fmaf(a.z, w20.w, fmaf(a.y, w10.w, fmaf(a.x, w00.w, acc[i][3]))));
            acc[i][4] = fmaf(a.w, w31.x, fmaf(a.z, w21.x, fmaf(a.y, w11.x, fmaf(a.x, w01.x, acc[i][4]))));
            acc[i][5] = fmaf(a.w, w31.y, fmaf(a.z, w21.y, fmaf(a.y, w11.y, fmaf(a.x, w01.y, acc[i][5]))));
            acc[i][6] = fmaf(a.w, w31.z, fmaf(a.z, w21.z, fmaf(a.y, w11.z, fmaf(a.x, w01.z, acc[i][6]))));
            acc[i][7] = fmaf(a.w, w31.w, fmaf(a.z, w21.w, fmaf(a.y, w11.w, fmaf(a.x, w01.w, acc[i][7]))));
        }
    }
    float4 bs0 = *(const float4*)(bias1 + j);
    float4 bs1 = *(const float4*)(bias1 + j + 4);
    #pragma unroll
    for (int i = 0; i < 8; i++) {
        int p = p0 + pg*8 + i;
        if (p < nl) {
            float4 r0, r1;
            r0.x = acc[i][0] + bs0.x; r0.y = acc[i][1] + bs0.y;
            r0.z = acc[i][2] + bs0.z; r0.w = acc[i][3] + bs0.w;
            r1.x = acc[i][4] + bs1.x; r1.y = acc[i][5] + bs1.y;
            r1.z = acc[i][6] + bs1.z; r1.w = acc[i][7] + bs1.w;
            float* dst = xproj + (((size_t)b*T_ + p) << 10) + j;
            *(float4*)dst       = r0;
            *(float4*)(dst + 4) = r1;
        }
    }
}

// ---------------- LSTM chain (R5, frozen): K-grouped float4 gate loads + raw barriers ----------------
__device__ __forceinline__ float sig_f(float x) { return 1.0f / (1.0f + __expf(-x)); }
__device__ __forceinline__ float tanh_f(float x) {
    float xc = fminf(fmaxf(x, -15.0f), 15.0f);
    float e  = __expf(-2.0f * xc);
    return (1.0f - e) / (1.0f + e);
}

__device__ __forceinline__ void lstm_chain(
    const float* __restrict__ Whh,     // [512][128] row-major, this dir
    const float* __restrict__ xp,      // xproj for this b: [1024][1024] gate-interleaved, bias folded
    float* __restrict__ outp,          // lstm_packed for this b: [1024][256]
    int p_base, int len, int dir, int rev,
    const float* __restrict__ h0, const float* __restrict__ c0,
    float* __restrict__ hT, float* __restrict__ cT)
{
    __shared__ __align__(16) float  h_sh[HD_];
    __shared__ __align__(16) float4 psum[4*HD_];   // [q][j], conflict-free lane order
    int t = threadIdx.x;          // 0..511
    int j = t & 127, q = t >> 7;  // per-wave q is uniform -> h reads are pure broadcast

    // Weights: gate rows j+128g, k in [32q, 32q+32). Pinned into regs (128/thread).
    float4 w[4][8];
    #pragma unroll
    for (int g = 0; g < 4; g++) {
        const float4* wr = (const float4*)(Whh + (size_t)(j + 128*g) * HD_ + 32*q);
        #pragma unroll
        for (int i = 0; i < 8; i++) { w[g][i] = wr[i]; PIN4(w[g][i]); }
    }

    float c_reg = 0.0f;
    if (t < HD_) {
        h_sh[t] = h0 ? h0[t] : 0.0f;
        c_reg   = c0 ? c0[t] : 0.0f;
    }
    __syncthreads();   // once; also drains h0/c0 loads — fine

    // x-contribution: one float4 per (p, j): gates i,f,g,o at n = dir*512 + j*4 + {0..3}
    const float4* xcol4 = (const float4*)(xp + (size_t)dir * G_) + j;
    const int     oco   = dir * HD_ + j;

    float4 xv[KS_];
    float  hbuf[KS_];

    for (int gs = 0; gs < len; gs += KS_) {
        // ---- group prologue: the ONLY global traffic. With BAR_LDS inner
        // barriers these loads/stores stay in flight across steps; the
        // compiler waits per-use with counted vmcnt instead of vmcnt(0).
        if (t < HD_) {
            if (gs > 0) {
                #pragma unroll
                for (int u = 0; u < KS_; u++) {          // prev group always full
                    int s = gs - KS_ + u;
                    int p = p_base + (rev ? (len - 1 - s) : s);
                    outp[(size_t)p * 256 + oco] = hbuf[u];
                }
            }
            #pragma unroll
            for (int u = 0; u < KS_; u++) {
                int s = gs + u;
                if (s < len) {
                    int p = p_base + (rev ? (len - 1 - s) : s);
                    xv[u] = xcol4[(size_t)p << 8];       // p*1024 floats = p*256 float4
                }
            }
        }
        // ---- 8 steps; barriers drain LDS only (no vmcnt(0)) ----
        #pragma unroll
        for (int u = 0; u < KS_; u++) {
            if (gs + u < len) {                          // block-uniform predicate
                const float4* hv = (const float4*)h_sh + q * 8;
                float4 a0 = make_float4(0.f,0.f,0.f,0.f);
                float4 a1 = a0, a2 = a0, a3 = a0;
                #pragma unroll
                for (int i = 0; i < 8; i++) {
                    float4 h4 = hv[i];
                    a0.x = fmaf(h4.x, w[0][i].x, a0.x); a0.y = fmaf(h4.y, w[0][i].y, a0.y);
                    a0.z = fmaf(h4.z, w[0][i].z, a0.z); a0.w = fmaf(h4.w, w[0][i].w, a0.w);
                    a1.x = fmaf(h4.x, w[1][i].x, a1.x); a1.y = fmaf(h4.y, w[1][i].y, a1.y);
                    a1.z = fmaf(h4.z, w[1][i].z, a1.z); a1.w = fmaf(h4.w, w[1][i].w, a1.w);
                    a2.x = fmaf(h4.x, w[2][i].x, a2.x); a2.y = fmaf(h4.y, w[2][i].y, a2.y);
                    a2.z = fmaf(h4.z, w[2][i].z, a2.z); a2.w = fmaf(h4.w, w[2][i].w, a2.w);
                    a3.x = fmaf(h4.x, w[3][i].x, a3.x); a3.y = fmaf(h4.y, w[3][i].y, a3.y);
                    a3.z = fmaf(h4.z, w[3][i].z, a3.z); a3.w = fmaf(h4.w, w[3][i].w, a3.w);
                }
                psum[q*128 + j] = make_float4((a0.x+a0.y)+(a0.z+a0.w),
                                              (a1.x+a1.y)+(a1.z+a1.w),
                                              (a2.x+a2.y)+(a2.z+a2.w),
                                              (a3.x+a3.y)+(a3.z+a3.w));
                BAR_LDS();
                if (t < HD_) {
                    float4 p0 = psum[j], p1 = psum[128 + j], p2 = psum[256 + j], p3 = psum[384 + j];
                    float gi = xv[u].x + ((p0.x + p1.x) + (p2.x + p3.x));
                    float gf = xv[u].y + ((p0.y + p1.y) + (p2.y + p3.y));
                    float gg = xv[u].z + ((p0.z + p1.z) + (p2.z + p3.z));
                    float go = xv[u].w + ((p0.w + p1.w) + (p2.w + p3.w));
                    float cn = sig_f(gf) * c_reg + sig_f(gi) * tanh_f(gg);
                    c_reg = cn;
                    float hn = sig_f(go) * tanh_f(cn);
                    h_sh[j] = hn;
                    hbuf[u] = hn;
                }
                BAR_LDS();
            }
        }
    }
    // final flush of the last (possibly partial) group
    if (t < HD_ && len > 0) {
        int gs = ((len - 1) / KS_) * KS_;
        #pragma unroll
        for (int u = 0; u < KS_; u++) {
            int s = gs + u;
            if (s < len) {
                int p = p_base + (rev ? (len - 1 - s) : s);
                outp[(size_t)p * 256 + oco] = hbuf[u];
            }
        }
    }
    if (hT != nullptr && t < HD_) { hT[t] = h_sh[t]; cT[t] = c_reg; }
}

__global__ void __launch_bounds__(512, 1)
lstm1_kernel(const int* __restrict__ lengths, const int* __restrict__ seg_off,
             const int* __restrict__ order1,
             const float* __restrict__ Whh_f, const float* __restrict__ Whh_b,
             const float* __restrict__ xproj, float* __restrict__ lstm_packed,
             float* __restrict__ hinit, float* __restrict__ cinit)
{
    int cid = blockIdx.x;                 // 512 = 256 (b,seg) LPT-ordered * 2dir
    int pr  = order1[cid >> 1];           // longest chains first
    int b = pr >> 3, seg = pr & 7, dir = cid & 1;
    int len = lengths[b*NSEG_ + seg];
    int pb  = seg_off[b*NSEG_ + seg];
    const float* Whh = dir ? Whh_b : Whh_f;
    float* hT = nullptr; float* cT = nullptr;
    if (seg == NSEG_ - 1) {               // final states feed LSTM2 init
        hT = hinit + (dir*B_ + b)*HD_;
        cT = cinit + (dir*B_ + b)*HD_;
    }
    lstm_chain(Whh, xproj + ((size_t)b << 20), lstm_packed + (size_t)b*T_*256,
               pb, len, dir, dir, nullptr, nullptr, hT, cT);
}

__global__ void __launch_bounds__(512, 1)
lstm2_kernel(const int* __restrict__ new_len,
             const float* __restrict__ Whh_f, const float* __restrict__ Whh_b,
             const float* __restrict__ xproj, float* __restrict__ lstm_packed,
             const float* __restrict__ hinit, const float* __restrict__ cinit)
{
    int cid = blockIdx.x;                 // 64 = 32b * 2dir
    int b = cid >> 1, dir = cid & 1;
    int len = new_len[b];
    const float* Whh = dir ? Whh_b : Whh_f;
    lstm_chain(Whh, xproj + ((size_t)b << 20), lstm_packed + (size_t)b*T_*256,
               0, len, dir, dir,
               hinit + (dir*B_ + b)*HD_, cinit + (dir*B_ + b)*HD_,
               nullptr, nullptr);
}

// ---------------- emission: em[b][p][s] = lstm2[b][p][:] . Wlin[s][:] + blin[s] ----------------
__global__ void __launch_bounds__(256)
emission_kernel(const float* __restrict__ lstm_packed, const float* __restrict__ Wlin,
                const float* __restrict__ blin, float* __restrict__ emis,
                const int* __restrict__ new_len)
{
    int b  = blockIdx.y;
    int nl = new_len[b];
    int p0 = blockIdx.x * 16;
    if (p0 >= nl) return;
    int pl = threadIdx.x >> 4, s = threadIdx.x & 15;
    int p  = p0 + pl;
    const float4* xr = (const float4*)(lstm_packed + ((size_t)b*T_ + p) * 256);
    const float4* wr = (const float4*)(Wlin + (size_t)s * 256);
    float ax = 0.f, ay = 0.f, az = 0.f, aw = 0.f;
    #pragma unroll
    for (int i = 0; i < 64; i++) {
        float4 a = xr[i]; float4 ww = wr[i];
        ax = fmaf(a.x, ww.x, ax); ay = fmaf(a.y, ww.y, ay);
        az = fmaf(a.z, ww.z, az); aw = fmaf(a.w, ww.w, aw);
    }
    if (p < nl) emis[((size_t)b*T_ + p)*K_ + s] = (ax + ay) + (az + aw) + blin[s];
}

// ---------------- Viterbi: one block (1 wave) per batch element ----------------
__global__ void __launch_bounds__(64)
viterbi_kernel(const float* __restrict__ emis, const float* __restrict__ start,
               const float* __restrict__ trans, const float* __restrict__ endv,
               const int* __restrict__ new_len, float* __restrict__ out)
{
    int b    = blockIdx.x;
    int nl   = new_len[b];
    int lane = threadIdx.x;          // 64 lanes: 4 q-groups x 16 states
    int s    = lane & 15, q4 = lane >> 4;

    __shared__ unsigned char hist[T_ * K_];   // 16 KB
    __shared__ unsigned char tagb[T_];

    float tr[4];
    #pragma unroll
    for (int jj = 0; jj < 4; jj++) tr[jj] = trans[(q4*4 + jj)*K_ + s];

    const float* em = emis + (size_t)b * T_ * K_;
    float sc = start[s] + em[s];     // p = 0 (always valid)

    for (int p = 1; p < nl; p++) {
        float e = em[p*K_ + s];
        float m = -3.4e38f; int a = 0;
        #pragma unroll
        for (int jj = 0; jj < 4; jj++) {
            int q   = q4*4 + jj;
            float sq = __shfl(sc, q, 16);
            float v  = sq + tr[jj];
            if (v > m) { m = v; a = q; }
        }
        #pragma unroll
        for (int d = 16; d < 64; d <<= 1) {
            float mo = __shfl_xor(m, d);
            int   ao = __shfl_xor(a, d);
            if (mo > m || (mo == m && ao < a)) { m = mo; a = ao; }
        }
        sc = m + e;
        if (lane < K_) hist[p*K_ + s] = (unsigned char)a;
    }

    float m = sc + endv[s]; int a = s;
    #pragma unroll
    for (int d = 1; d < 16; d <<= 1) {
        float mo = __shfl_xor(m, d);
        int   ao = __shfl_xor(a, d);
        if (mo > m || (mo == m && ao < a)) { m = mo; a = ao; }
    }
    int last = a;
    if (lane == 0) out[T_*B_ + b] = m;
    __syncthreads();

    for (int i = lane; i < T_; i += 64) tagb[i] = (unsigned char)last;
    __syncthreads();
    if (lane == 0) {
        int cur = last;
        for (int j = nl - 2; j >= 0; j--) {
            cur = hist[(j+1)*K_ + cur];
            tagb[j] = (unsigned char)cur;
        }
    }
    __syncthreads();
    for (int i = lane; i < T_; i += 64) out[(size_t)i*B_ + b] = (float)tagb[i];
}

// ---------------- host ----------------
extern "C" void kernel_launch(void* const* d_in, const int* in_sizes, int n_in,
                              void* d_out, int out_size, void* d_ws, size_t ws_size,
                              hipStream_t stream)
{
    (void)in_sizes; (void)n_in; (void)out_size; (void)ws_size;
    const int*   texts   = (const int*)  d_in[0];
    const int*   lengths = (const int*)  d_in[1];
    const float* emb     = (const float*)d_in[2];
    const float* Wih_f   = (const float*)d_in[3];
    const float* Whh_f   = (const float*)d_in[4];
    const float* bih_f   = (const float*)d_in[5];
    const float* bhh_f   = (const float*)d_in[6];
    const float* Wih_b   = (const float*)d_in[7];
    const float* Whh_b   = (const float*)d_in[8];
    const float* bih_b   = (const float*)d_in[9];
    const float* bhh_b   = (const float*)d_in[10];
    const float* Wlin    = (const float*)d_in[11];
    const float* blin    = (const float*)d_in[12];
    const float* c_start = (const float*)d_in[13];
    const float* c_trans = (const float*)d_in[14];
    const float* c_end   = (const float*)d_in[15];
    float* out = (float*)d_out;

    // workspace carve (~163 MB total, all 16B-aligned)
    char* w = (char*)d_ws;
    int*   seg_off     = (int*)(w);                      // 256 ints
    int*   new_len     = (int*)(w + 1024);               // 32 ints
    int*   order1      = (int*)(w + 2048);               // 256 ints
    float* bias1       = (float*)(w + 4096);             // 1024 f
    float* WT1         = (float*)(w + 8192);             // 262144 f (1 MB)
    float* hinit       = (float*)(w + 8192 + 1048576);   // 8192 f
    float* cinit       = hinit + 8192;                   // 8192 f
    float* lstm_packed = cinit + 8192;                   // 32*1024*256 f (32 MB)
    float* xproj       = lstm_packed + (size_t)B_*T_*256;    // 32*1024*1024 f (128 MB)
    float* emis        = xproj + ((size_t)B_ << 20);         // 32*1024*16 f (2 MB)

    prep_kernel<<<128, 256, 0, stream>>>(lengths, seg_off, new_len, order1,
                                         bih_f, bhh_f, bih_b, bhh_b, bias1,
                                         Wih_f, Wih_b, WT1);
    proj_kernel<0><<<dim3(32, 2, B_), 256, 0, stream>>>(texts, emb, WT1, bias1,
                                                        lstm_packed, xproj, seg_off, new_len);
    lstm1_kernel<<<512, 512, 0, stream>>>(lengths, seg_off, order1, Whh_f, Whh_b,
                                          xproj, lstm_packed, hinit, cinit);
    proj_kernel<1><<<dim3(32, 2, B_), 256, 0, stream>>>(texts, emb, WT1, bias1,
                                                        lstm_packed, xproj, seg_off, new_len);
    lstm2_kernel<<<64, 512, 0, stream>>>(new_len, Whh_f, Whh_b,
                                         xproj, lstm_packed, hinit, cinit);
    emission_kernel<<<dim3(64, B_), 256, 0, stream>>>(lstm_packed, Wlin, blin, emis, new_len);
    viterbi_kernel<<<B_, 64, 0, stream>>>(emis, c_start, c_trans, c_end, new_len, out);
}

// Round 11
// 1551.916 us; speedup vs baseline: 1.1592x; 1.0066x over previous
//
#include <hip/hip_runtime.h>
#include <cstdint>
#include <cstddef>

// BiLSTM-CRF forward, MI355X fp32 implementation.
// Pipeline: prep -> proj1(emb gather GEMM) -> lstm1(256 blocks x 2 chains,
//           complement-paired) -> proj2 -> lstm2(64 chains) -> emission
//           -> viterbi(+backtrace).
//
// R13 (measured 1562.1us, best): proj 8x8 retile (proj now ~FMA-floor-bound,
//   closed) + LPT launch order (the +26us).
// R14 (this round): lstm1 STATIC COMPLEMENT PAIRING.
//   R13's LPT is list-scheduling with jobs = 2x machines: CUs finishing the
//   shortest first-round chain (~97 steps) greedily take the LONGEST
//   remaining (~96) -> makespan ~193 steps. Static pairing (block k runs
//   rank-k unit then rank-(511-k) unit) gives complement sums ~129-135
//   steps, deterministic, no HW-dispatch-order dependence. ~45-50us.
//   LDS reuse across the two lstm_chain calls: B's h_sh init is same-thread
//   ordered after A's epilogue read; B's __syncthreads covers the rest.
// Frozen: lstm2 (register wall: 120 VGPR + 128 AGPR = 248/wave, 2-barrier
//   serial step; closed branches: pairing, in-wave reduce, DPP butterfly).

#define B_    32
#define NSEG_ 8
#define S_    128
#define T_    1024
#define E_    256
#define HD_   128
#define G_    512   // 4*HD
#define K_    16
#define KS_   8     // steps per group (global-drain amortization)

#define PIN4(v) asm volatile("" : "+v"((v).x), "+v"((v).y), "+v"((v).z), "+v"((v).w))

// Barrier that does NOT drain vmcnt: LDS writes made visible (lgkmcnt(0)),
// rendezvous, then a hard scheduling fence so following LDS reads can't
// hoist above the barrier (rule #18).
#define BAR_LDS() do {                                        \
    asm volatile("s_waitcnt lgkmcnt(0)" ::: "memory");        \
    __builtin_amdgcn_s_barrier();                             \
    __builtin_amdgcn_sched_barrier(0);                        \
} while (0)

// ---------------- prep: seg offsets, fused+permuted bias, permuted Wih^T, rank order ----------------
// Gate-interleaved column n in [0,1024): dir=n>>9, j=(n>>2)&127, g=n&3
// maps to LSTM gate row (g*128+j) of direction dir.
__global__ void prep_kernel(const int* __restrict__ lengths,
                            int* __restrict__ seg_off, int* __restrict__ new_len,
                            int* __restrict__ order1,
                            const float* __restrict__ bih_f, const float* __restrict__ bhh_f,
                            const float* __restrict__ bih_b, const float* __restrict__ bhh_b,
                            float* __restrict__ bias1,
                            const float* __restrict__ Wih_f, const float* __restrict__ Wih_b,
                            float* __restrict__ WT1)
{
    __shared__ int s_len[256];
    __shared__ int s_ord[256];
    int gtid = blockIdx.x * blockDim.x + threadIdx.x;
    if (gtid < B_) {
        int acc = 0;
        for (int s = 0; s < NSEG_; s++) { seg_off[gtid*NSEG_ + s] = acc; acc += lengths[gtid*NSEG_ + s]; }
        new_len[gtid] = acc;
    }
    if (gtid < 1024) {
        int n = gtid, dir = n >> 9, j = (n >> 2) & 127, g = n & 3;
        int row = g*128 + j;
        bias1[n] = dir ? (bih_b[row] + bhh_b[row]) : (bih_f[row] + bhh_f[row]);
    }
    // Rank order over the 256 (b,seg) chains (both dirs share a length):
    // rank-sort by length desc (index asc tiebreak) -> order1[rank] = b*8+seg.
    if (blockIdx.x == 0) {
        int t = threadIdx.x;              // 0..255
        s_len[t] = lengths[t];
        __syncthreads();
        int my = s_len[t], rank = 0;
        for (int u = 0; u < 256; u++) {
            int lu = s_len[u];
            if (lu > my || (lu == my && u < t)) rank++;
        }
        s_ord[rank] = t;
        __syncthreads();
        order1[t] = s_ord[t];
    }
    // WT1[k][n] (256 x 1024): column n holds Wih row (g*128+j) of dir.
    for (int e = gtid; e < 256*1024; e += gridDim.x * blockDim.x) {
        int k = e >> 10, n = e & 1023;
        int dir = n >> 9, j = (n >> 2) & 127, g = n & 3;
        int row = g*128 + j;
        WT1[e] = dir ? Wih_b[row*E_ + k] : Wih_f[row*E_ + k];
    }
}

// ---------------- projection GEMM: xproj[b][p][n] = A[p][:] . WT1[:][n] + bias1[n] ----------------
// Tile: 32 rows x 512 cols per block; thread = 8 rows x 8 cols.
template <int MODE>
__global__ void __launch_bounds__(256, 2)
proj_kernel(const int* __restrict__ texts, const float* __restrict__ emb,
            const float* __restrict__ WT1, const float* __restrict__ bias1,
            const float* __restrict__ lstm_packed, float* __restrict__ xproj,
            const int* __restrict__ seg_off, const int* __restrict__ new_len)
{
    int b  = blockIdx.z;
    int nl = new_len[b];
    int p0 = blockIdx.x * 32;
    if (p0 >= nl) return;
    int j0 = blockIdx.y * 512;

    __shared__ __align__(16) float As[32][256];
    __shared__ const float* rowp[32];
    int tid = threadIdx.x;
    if (tid < 32) {
        int p = p0 + tid;
        const float* r = emb;  // dummy row for invalid p
        if (p < nl) {
            if (MODE == 0) {
                int sg = 0;
                #pragma unroll
                for (int q = 1; q < NSEG_; q++) if (seg_off[b*NSEG_ + q] <= p) sg = q;
                int t   = p - seg_off[b*NSEG_ + sg];
                int tok = texts[(b*NSEG_ + sg)*S_ + t];
                r = emb + (size_t)tok * E_;
            } else {
                r = lstm_packed + ((size_t)b*T_ + p) * 256;
            }
        }
        rowp[tid] = r;
    }
    __syncthreads();
    #pragma unroll 4
    for (int i = 0; i < 32; i++) As[i][tid] = rowp[i][tid];
    __syncthreads();

    int pg = tid >> 6;        // 0..3 -> rows pg*8 .. +7
    int jg = tid & 63;        // cols j0 + jg*8 .. +7
    int j  = j0 + jg*8;
    float acc[8][8];
    #pragma unroll
    for (int i = 0; i < 8; i++)
        #pragma unroll
        for (int c = 0; c < 8; c++) acc[i][c] = 0.f;

    const float* wbase = WT1 + j;
    for (int k = 0; k < 256; k += 4) {
        float4 w00 = *(const float4*)(wbase + (size_t)(k+0)*1024);
        float4 w01 = *(const float4*)(wbase + (size_t)(k+0)*1024 + 4);
        float4 w10 = *(const float4*)(wbase + (size_t)(k+1)*1024);
        float4 w11 = *(const float4*)(wbase + (size_t)(k+1)*1024 + 4);
        float4 w20 = *(const float4*)(wbase + (size_t)(k+2)*1024);
        float4 w21 = *(const float4*)(wbase + (size_t)(k+2)*1024 + 4);
        float4 w30 = *(const float4*)(wbase + (size_t)(k+3)*1024);
        float4 w31 = *(const float4*)(wbase + (size_t)(k+3)*1024 + 4);
        #pragma unroll
        for (int i = 0; i < 8; i++) {
            float4 a = *(const float4*)&As[pg*8 + i][k];
            acc[i][0] = fmaf(a.w, w30.x, fmaf(a.z, w20.x, fmaf(a.y, w10.x, fmaf(a.x, w00.x, acc[i][0]))));
            acc[i][1] = fmaf(a.w, w30.y, fmaf(a.z, w20.y, fmaf(a.y, w10.y, fmaf(a.x, w00.y, acc[i][1]))));
            acc[i][2] = fmaf(a.w, w30.z, fmaf(a.z, w20.z, fmaf(a.y, w10.z, fmaf(a.x, w00.z, acc[i][2]))));
            acc[i][3] = fmaf(a.w, w30.w, fmaf(a.z, w20.w, fmaf(a.y, w10.w, fmaf(a.x, w00.w, acc[i][3]))));
            acc[i][4] = fmaf(a.w, w31.x, fmaf(a.z, w21.x, fmaf(a.y, w11.x, fmaf(a.x, w01.x, acc[i][4]))));
            acc[i][5] = fmaf(a.w, w31.y, fmaf(a.z, w21.y, fmaf(a.y, w11.y, fmaf(a.x, w01.y, acc[i][5]))));
            acc[i][6] = fmaf(a.w, w31.z, fmaf(a.z, w21.z, fmaf(a.y, w11.z, fmaf(a.x, w01.z, acc[i][6]))));
            acc[i][7] = fmaf(a.w, w31.w, fmaf(a.z, w21.w, fmaf(a.y, w11.w, fmaf(a.x, w01.w, acc[i][7]))));
        }
    }
    float4 bs0 = *(const float4*)(bias1 + j);
    float4 bs1 = *(const float4*)(bias1 + j + 4);
    #pragma unroll
    for (int i = 0; i < 8; i++) {
        int p = p0 + pg*8 + i;
        if (p < nl) {
            float4 r0, r1;
            r0.x = acc[i][0] + bs0.x; r0.y = acc[i][1] + bs0.y;
            r0.z = acc[i][2] + bs0.z; r0.w = acc[i][3] + bs0.w;
            r1.x = acc[i][4] + bs1.x; r1.y = acc[i][5] + bs1.y;
            r1.z = acc[i][6] + bs1.z; r1.w = acc[i][7] + bs1.w;
            float* dst = xproj + (((size_t)b*T_ + p) << 10) + j;
            *(float4*)dst       = r0;
            *(float4*)(dst + 4) = r1;
        }
    }
}

// ---------------- LSTM chain (R5, frozen): K-grouped float4 gate loads + raw barriers ----------------
__device__ __forceinline__ float sig_f(float x) { return 1.0f / (1.0f + __expf(-x)); }
__device__ __forceinline__ float tanh_f(float x) {
    float xc = fminf(fmaxf(x, -15.0f), 15.0f);
    float e  = __expf(-2.0f * xc);
    return (1.0f - e) / (1.0f + e);
}

__device__ __forceinline__ void lstm_chain(
    const float* __restrict__ Whh,     // [512][128] row-major, this dir
    const float* __restrict__ xp,      // xproj for this b: [1024][1024] gate-interleaved, bias folded
    float* __restrict__ outp,          // lstm_packed for this b: [1024][256]
    int p_base, int len, int dir, int rev,
    const float* __restrict__ h0, const float* __restrict__ c0,
    float* __restrict__ hT, float* __restrict__ cT)
{
    __shared__ __align__(16) float  h_sh[HD_];
    __shared__ __align__(16) float4 psum[4*HD_];   // [q][j], conflict-free lane order
    int t = threadIdx.x;          // 0..511
    int j = t & 127, q = t >> 7;  // per-wave q is uniform -> h reads are pure broadcast

    // Weights: gate rows j+128g, k in [32q, 32q+32). Pinned into regs (128/thread).
    float4 w[4][8];
    #pragma unroll
    for (int g = 0; g < 4; g++) {
        const float4* wr = (const float4*)(Whh + (size_t)(j + 128*g) * HD_ + 32*q);
        #pragma unroll
        for (int i = 0; i < 8; i++) { w[g][i] = wr[i]; PIN4(w[g][i]); }
    }

    float c_reg = 0.0f;
    if (t < HD_) {
        h_sh[t] = h0 ? h0[t] : 0.0f;
        c_reg   = c0 ? c0[t] : 0.0f;
    }
    __syncthreads();   // once; also drains h0/c0 loads — fine

    // x-contribution: one float4 per (p, j): gates i,f,g,o at n = dir*512 + j*4 + {0..3}
    const float4* xcol4 = (const float4*)(xp + (size_t)dir * G_) + j;
    const int     oco   = dir * HD_ + j;

    float4 xv[KS_];
    float  hbuf[KS_];

    for (int gs = 0; gs < len; gs += KS_) {
        // ---- group prologue: the ONLY global traffic. With BAR_LDS inner
        // barriers these loads/stores stay in flight across steps; the
        // compiler waits per-use with counted vmcnt instead of vmcnt(0).
        if (t < HD_) {
            if (gs > 0) {
                #pragma unroll
                for (int u = 0; u < KS_; u++) {          // prev group always full
                    int s = gs - KS_ + u;
                    int p = p_base + (rev ? (len - 1 - s) : s);
                    outp[(size_t)p * 256 + oco] = hbuf[u];
                }
            }
            #pragma unroll
            for (int u = 0; u < KS_; u++) {
                int s = gs + u;
                if (s < len) {
                    int p = p_base + (rev ? (len - 1 - s) : s);
                    xv[u] = xcol4[(size_t)p << 8];       // p*1024 floats = p*256 float4
                }
            }
        }
        // ---- 8 steps; barriers drain LDS only (no vmcnt(0)) ----
        #pragma unroll
        for (int u = 0; u < KS_; u++) {
            if (gs + u < len) {                          // block-uniform predicate
                const float4* hv = (const float4*)h_sh + q * 8;
                float4 a0 = make_float4(0.f,0.f,0.f,0.f);
                float4 a1 = a0, a2 = a0, a3 = a0;
                #pragma unroll
                for (int i = 0; i < 8; i++) {
                    float4 h4 = hv[i];
                    a0.x = fmaf(h4.x, w[0][i].x, a0.x); a0.y = fmaf(h4.y, w[0][i].y, a0.y);
                    a0.z = fmaf(h4.z, w[0][i].z, a0.z); a0.w = fmaf(h4.w, w[0][i].w, a0.w);
                    a1.x = fmaf(h4.x, w[1][i].x, a1.x); a1.y = fmaf(h4.y, w[1][i].y, a1.y);
                    a1.z = fmaf(h4.z, w[1][i].z, a1.z); a1.w = fmaf(h4.w, w[1][i].w, a1.w);
                    a2.x = fmaf(h4.x, w[2][i].x, a2.x); a2.y = fmaf(h4.y, w[2][i].y, a2.y);
                    a2.z = fmaf(h4.z, w[2][i].z, a2.z); a2.w = fmaf(h4.w, w[2][i].w, a2.w);
                    a3.x = fmaf(h4.x, w[3][i].x, a3.x); a3.y = fmaf(h4.y, w[3][i].y, a3.y);
                    a3.z = fmaf(h4.z, w[3][i].z, a3.z); a3.w = fmaf(h4.w, w[3][i].w, a3.w);
                }
                psum[q*128 + j] = make_float4((a0.x+a0.y)+(a0.z+a0.w),
                                              (a1.x+a1.y)+(a1.z+a1.w),
                                              (a2.x+a2.y)+(a2.z+a2.w),
                                              (a3.x+a3.y)+(a3.z+a3.w));
                BAR_LDS();
                if (t < HD_) {
                    float4 p0 = psum[j], p1 = psum[128 + j], p2 = psum[256 + j], p3 = psum[384 + j];
                    float gi = xv[u].x + ((p0.x + p1.x) + (p2.x + p3.x));
                    float gf = xv[u].y + ((p0.y + p1.y) + (p2.y + p3.y));
                    float gg = xv[u].z + ((p0.z + p1.z) + (p2.z + p3.z));
                    float go = xv[u].w + ((p0.w + p1.w) + (p2.w + p3.w));
                    float cn = sig_f(gf) * c_reg + sig_f(gi) * tanh_f(gg);
                    c_reg = cn;
                    float hn = sig_f(go) * tanh_f(cn);
                    h_sh[j] = hn;
                    hbuf[u] = hn;
                }
                BAR_LDS();
            }
        }
    }
    // final flush of the last (possibly partial) group
    if (t < HD_ && len > 0) {
        int gs = ((len - 1) / KS_) * KS_;
        #pragma unroll
        for (int u = 0; u < KS_; u++) {
            int s = gs + u;
            if (s < len) {
                int p = p_base + (rev ? (len - 1 - s) : s);
                outp[(size_t)p * 256 + oco] = hbuf[u];
            }
        }
    }
    if (hT != nullptr && t < HD_) { hT[t] = h_sh[t]; cT[t] = c_reg; }
}

// lstm1: 256 blocks, each runs TWO (chain,dir) units: rank-order unit k,
// then unit 511-k. Complement pairing of sorted lengths -> per-block total
// ~len_min+len_max ~= constant -> deterministic near-optimal makespan.
__global__ void __launch_bounds__(512, 1)
lstm1_kernel(const int* __restrict__ lengths, const int* __restrict__ seg_off,
             const int* __restrict__ order1,
             const float* __restrict__ Whh_f, const float* __restrict__ Whh_b,
             const float* __restrict__ xproj, float* __restrict__ lstm_packed,
             float* __restrict__ hinit, float* __restrict__ cinit)
{
    int k = blockIdx.x;                   // 0..255
    #pragma unroll
    for (int half = 0; half < 2; half++) {
        int u   = half ? (511 - k) : k;   // unit id: rank*2 + dir
        int r   = u >> 1, dir = u & 1;
        int pr  = order1[r];
        int b   = pr >> 3, seg = pr & 7;
        int len = lengths[b*NSEG_ + seg];
        int pb  = seg_off[b*NSEG_ + seg];
        const float* Whh = dir ? Whh_b : Whh_f;
        float* hT = nullptr; float* cT = nullptr;
        if (seg == NSEG_ - 1) {           // final states feed LSTM2 init
            hT = hinit + (dir*B_ + b)*HD_;
            cT = cinit + (dir*B_ + b)*HD_;
        }
        lstm_chain(Whh, xproj + ((size_t)b << 20), lstm_packed + (size_t)b*T_*256,
                   pb, len, dir, dir, nullptr, nullptr, hT, cT);
        // Between the two chains: chain B's lstm_chain re-inits h_sh (same
        // thread that read it in A's epilogue) and has its own __syncthreads
        // before first use — no extra barrier needed.
    }
}

__global__ void __launch_bounds__(512, 1)
lstm2_kernel(const int* __restrict__ new_len,
             const float* __restrict__ Whh_f, const float* __restrict__ Whh_b,
             const float* __restrict__ xproj, float* __restrict__ lstm_packed,
             const float* __restrict__ hinit, const float* __restrict__ cinit)
{
    int cid = blockIdx.x;                 // 64 = 32b * 2dir
    int b = cid >> 1, dir = cid & 1;
    int len = new_len[b];
    const float* Whh = dir ? Whh_b : Whh_f;
    lstm_chain(Whh, xproj + ((size_t)b << 20), lstm_packed + (size_t)b*T_*256,
               0, len, dir, dir,
               hinit + (dir*B_ + b)*HD_, cinit + (dir*B_ + b)*HD_,
               nullptr, nullptr);
}

// ---------------- emission: em[b][p][s] = lstm2[b][p][:] . Wlin[s][:] + blin[s] ----------------
__global__ void __launch_bounds__(256)
emission_kernel(const float* __restrict__ lstm_packed, const float* __restrict__ Wlin,
                const float* __restrict__ blin, float* __restrict__ emis,
                const int* __restrict__ new_len)
{
    int b  = blockIdx.y;
    int nl = new_len[b];
    int p0 = blockIdx.x * 16;
    if (p0 >= nl) return;
    int pl = threadIdx.x >> 4, s = threadIdx.x & 15;
    int p  = p0 + pl;
    const float4* xr = (const float4*)(lstm_packed + ((size_t)b*T_ + p) * 256);
    const float4* wr = (const float4*)(Wlin + (size_t)s * 256);
    float ax = 0.f, ay = 0.f, az = 0.f, aw = 0.f;
    #pragma unroll
    for (int i = 0; i < 64; i++) {
        float4 a = xr[i]; float4 ww = wr[i];
        ax = fmaf(a.x, ww.x, ax); ay = fmaf(a.y, ww.y, ay);
        az = fmaf(a.z, ww.z, az); aw = fmaf(a.w, ww.w, aw);
    }
    if (p < nl) emis[((size_t)b*T_ + p)*K_ + s] = (ax + ay) + (az + aw) + blin[s];
}

// ---------------- Viterbi: one block (1 wave) per batch element ----------------
__global__ void __launch_bounds__(64)
viterbi_kernel(const float* __restrict__ emis, const float* __restrict__ start,
               const float* __restrict__ trans, const float* __restrict__ endv,
               const int* __restrict__ new_len, float* __restrict__ out)
{
    int b    = blockIdx.x;
    int nl   = new_len[b];
    int lane = threadIdx.x;          // 64 lanes: 4 q-groups x 16 states
    int s    = lane & 15, q4 = lane >> 4;

    __shared__ unsigned char hist[T_ * K_];   // 16 KB
    __shared__ unsigned char tagb[T_];

    float tr[4];
    #pragma unroll
    for (int jj = 0; jj < 4; jj++) tr[jj] = trans[(q4*4 + jj)*K_ + s];

    const float* em = emis + (size_t)b * T_ * K_;
    float sc = start[s] + em[s];     // p = 0 (always valid)

    for (int p = 1; p < nl; p++) {
        float e = em[p*K_ + s];
        float m = -3.4e38f; int a = 0;
        #pragma unroll
        for (int jj = 0; jj < 4; jj++) {
            int q   = q4*4 + jj;
            float sq = __shfl(sc, q, 16);
            float v  = sq + tr[jj];
            if (v > m) { m = v; a = q; }
        }
        #pragma unroll
        for (int d = 16; d < 64; d <<= 1) {
            float mo = __shfl_xor(m, d);
            int   ao = __shfl_xor(a, d);
            if (mo > m || (mo == m && ao < a)) { m = mo; a = ao; }
        }
        sc = m + e;
        if (lane < K_) hist[p*K_ + s] = (unsigned char)a;
    }

    float m = sc + endv[s]; int a = s;
    #pragma unroll
    for (int d = 1; d < 16; d <<= 1) {
        float mo = __shfl_xor(m, d);
        int   ao = __shfl_xor(a, d);
        if (mo > m || (mo == m && ao < a)) { m = mo; a = ao; }
    }
    int last = a;
    if (lane == 0) out[T_*B_ + b] = m;
    __syncthreads();

    for (int i = lane; i < T_; i += 64) tagb[i] = (unsigned char)last;
    __syncthreads();
    if (lane == 0) {
        int cur = last;
        for (int j = nl - 2; j >= 0; j--) {
            cur = hist[(j+1)*K_ + cur];
            tagb[j] = (unsigned char)cur;
        }
    }
    __syncthreads();
    for (int i = lane; i < T_; i += 64) out[(size_t)i*B_ + b] = (float)tagb[i];
}

// ---------------- host ----------------
extern "C" void kernel_launch(void* const* d_in, const int* in_sizes, int n_in,
                              void* d_out, int out_size, void* d_ws, size_t ws_size,
                              hipStream_t stream)
{
    (void)in_sizes; (void)n_in; (void)out_size; (void)ws_size;
    const int*   texts   = (const int*)  d_in[0];
    const int*   lengths = (const int*)  d_in[1];
    const float* emb     = (const float*)d_in[2];
    const float* Wih_f   = (const float*)d_in[3];
    const float* Whh_f   = (const float*)d_in[4];
    const float* bih_f   = (const float*)d_in[5];
    const float* bhh_f   = (const float*)d_in[6];
    const float* Wih_b   = (const float*)d_in[7];
    const float* Whh_b   = (const float*)d_in[8];
    const float* bih_b   = (const float*)d_in[9];
    const float* bhh_b   = (const float*)d_in[10];
    const float* Wlin    = (const float*)d_in[11];
    const float* blin    = (const float*)d_in[12];
    const float* c_start = (const float*)d_in[13];
    const float* c_trans = (const float*)d_in[14];
    const float* c_end   = (const float*)d_in[15];
    float* out = (float*)d_out;

    // workspace carve (~163 MB total, all 16B-aligned)
    char* w = (char*)d_ws;
    int*   seg_off     = (int*)(w);                      // 256 ints
    int*   new_len     = (int*)(w + 1024);               // 32 ints
    int*   order1      = (int*)(w + 2048);               // 256 ints
    float* bias1       = (float*)(w + 4096);             // 1024 f
    float* WT1         = (float*)(w + 8192);             // 262144 f (1 MB)
    float* hinit       = (float*)(w + 8192 + 1048576);   // 8192 f
    float* cinit       = hinit + 8192;                   // 8192 f
    float* lstm_packed = cinit + 8192;                   // 32*1024*256 f (32 MB)
    float* xproj       = lstm_packed + (size_t)B_*T_*256;    // 32*1024*1024 f (128 MB)
    float* emis        = xproj + ((size_t)B_ << 20);         // 32*1024*16 f (2 MB)

    prep_kernel<<<128, 256, 0, stream>>>(lengths, seg_off, new_len, order1,
                                         bih_f, bhh_f, bih_b, bhh_b, bias1,
                                         Wih_f, Wih_b, WT1);
    proj_kernel<0><<<dim3(32, 2, B_), 256, 0, stream>>>(texts, emb, WT1, bias1,
                                                        lstm_packed, xproj, seg_off, new_len);
    lstm1_kernel<<<256, 512, 0, stream>>>(lengths, seg_off, order1, Whh_f, Whh_b,
                                          xproj, lstm_packed, hinit, cinit);
    proj_kernel<1><<<dim3(32, 2, B_), 256, 0, stream>>>(texts, emb, WT1, bias1,
                                                        lstm_packed, xproj, seg_off, new_len);
    lstm2_kernel<<<64, 512, 0, stream>>>(new_len, Whh_f, Whh_b,
                                         xproj, lstm_packed, hinit, cinit);
    emission_kernel<<<dim3(64, B_), 256, 0, stream>>>(lstm_packed, Wlin, blin, emis, new_len);
    viterbi_kernel<<<B_, 64, 0, stream>>>(emis, c_start, c_trans, c_end, new_len, out);
}